// Round 1
// baseline (975.010 us; speedup 1.0000x reference)
//
#include <hip/hip_runtime.h>
#include <hip/hip_bf16.h>
#include <cstdint>

static __device__ __forceinline__ float lrelu(float x) { return x > 0.f ? x : 0.2f * x; }

// ---------------------------------------------------------------------------
// GEMM: C[M,Nout] = A[M,256] @ B[256,Nout] (+bias)(+relu).  K hardcoded = 256.
// 128x64 tile, BK=64, 256 threads, 8x4 micro-tile (rows interleaved by 16).
// ---------------------------------------------------------------------------
template <bool BIAS, bool RELU>
__global__ __launch_bounds__(256) void gemm_k256(
    const float* __restrict__ A, const float* __restrict__ B,
    const float* __restrict__ bias, float* __restrict__ C, int M, int Nout) {
  __shared__ float As[128 * 68];  // +4 pad keeps float4 alignment, kills conflicts
  __shared__ float Ws[64 * 64];
  const int t = threadIdx.x;
  const int row0 = blockIdx.x * 128;
  const int c0 = blockIdx.y * 64;
  const int tc = t & 15, tr = t >> 4;  // 16 col-threads x 16 row-threads

  float acc[8][4];
#pragma unroll
  for (int i = 0; i < 8; ++i) {
    acc[i][0] = 0.f; acc[i][1] = 0.f; acc[i][2] = 0.f; acc[i][3] = 0.f;
  }

  for (int k0 = 0; k0 < 256; k0 += 64) {
#pragma unroll
    for (int i = 0; i < 8; ++i) {  // A tile: 128 rows x 64 k
      int idx = t + i * 256;
      int r = idx >> 4, kq = idx & 15;
      float4 v = make_float4(0.f, 0.f, 0.f, 0.f);
      int gr = row0 + r;
      if (gr < M) v = *(const float4*)(A + (size_t)gr * 256 + k0 + kq * 4);
      *(float4*)&As[r * 68 + kq * 4] = v;
    }
#pragma unroll
    for (int i = 0; i < 4; ++i) {  // W tile: 64 k x 64 cols
      int idx = t + i * 256;
      int wr = idx >> 4, wc = idx & 15;
      *(float4*)&Ws[wr * 64 + wc * 4] =
          *(const float4*)(B + (size_t)(k0 + wr) * Nout + c0 + wc * 4);
    }
    __syncthreads();
#pragma unroll 4
    for (int kk = 0; kk < 64; kk += 4) {
      float4 w0 = *(float4*)&Ws[(kk + 0) * 64 + tc * 4];
      float4 w1 = *(float4*)&Ws[(kk + 1) * 64 + tc * 4];
      float4 w2 = *(float4*)&Ws[(kk + 2) * 64 + tc * 4];
      float4 w3 = *(float4*)&Ws[(kk + 3) * 64 + tc * 4];
#pragma unroll
      for (int i = 0; i < 8; ++i) {
        float4 a = *(float4*)&As[(i * 16 + tr) * 68 + kk];
        acc[i][0] += a.x * w0.x + a.y * w1.x + a.z * w2.x + a.w * w3.x;
        acc[i][1] += a.x * w0.y + a.y * w1.y + a.z * w2.y + a.w * w3.y;
        acc[i][2] += a.x * w0.z + a.y * w1.z + a.z * w2.z + a.w * w3.z;
        acc[i][3] += a.x * w0.w + a.y * w1.w + a.z * w2.w + a.w * w3.w;
      }
    }
    __syncthreads();
  }

  float4 b4 = make_float4(0.f, 0.f, 0.f, 0.f);
  if (BIAS) b4 = *(const float4*)(bias + c0 + tc * 4);
#pragma unroll
  for (int i = 0; i < 8; ++i) {
    int gr = row0 + i * 16 + tr;
    if (gr < M) {
      float4 o;
      o.x = acc[i][0] + b4.x;
      o.y = acc[i][1] + b4.y;
      o.z = acc[i][2] + b4.z;
      o.w = acc[i][3] + b4.w;
      if (RELU) {
        o.x = fmaxf(o.x, 0.f); o.y = fmaxf(o.y, 0.f);
        o.z = fmaxf(o.z, 0.f); o.w = fmaxf(o.w, 0.f);
      }
      *(float4*)(C + (size_t)gr * Nout + c0 + tc * 4) = o;
    }
  }
}

// ---------------------------------------------------------------------------
// Attention logits, layer 1: al[n][h] = sum_c xp[n][h*64+c] * a[h*64+c]
// one wave per node, butterfly reduce.
// ---------------------------------------------------------------------------
__global__ __launch_bounds__(256) void al1_kernel(
    const float* __restrict__ xp, const float* __restrict__ asrc,
    const float* __restrict__ adst, float* __restrict__ als,
    float* __restrict__ ald, int nn) {
  int wid = (blockIdx.x * blockDim.x + threadIdx.x) >> 6;
  int lane = threadIdx.x & 63;
  if (wid >= nn) return;
#pragma unroll
  for (int h = 0; h < 4; ++h) {
    float x = xp[(size_t)wid * 256 + h * 64 + lane];
    float ps = x * asrc[h * 64 + lane];
    float pd = x * adst[h * 64 + lane];
#pragma unroll
    for (int o = 32; o; o >>= 1) {
      ps += __shfl_xor(ps, o, 64);
      pd += __shfl_xor(pd, o, 64);
    }
    if (lane == 0) {
      als[wid * 4 + h] = ps;
      ald[wid * 4 + h] = pd;
    }
  }
}

// Layer 2 (1 head): al[n] = sum_c xp2[n][c] * a[c]
__global__ __launch_bounds__(256) void al2_kernel(
    const float* __restrict__ xp2, const float* __restrict__ asrc,
    const float* __restrict__ adst, float* __restrict__ als,
    float* __restrict__ ald, int nn) {
  int wid = (blockIdx.x * blockDim.x + threadIdx.x) >> 6;
  int lane = threadIdx.x & 63;
  if (wid >= nn) return;
  float x = xp2[(size_t)wid * 64 + lane];
  float ps = x * asrc[lane];
  float pd = x * adst[lane];
#pragma unroll
  for (int o = 32; o; o >>= 1) {
    ps += __shfl_xor(ps, o, 64);
    pd += __shfl_xor(pd, o, 64);
  }
  if (lane == 0) {
    als[wid] = ps;
    ald[wid] = pd;
  }
}

// ---------------------------------------------------------------------------
// CSR build
// ---------------------------------------------------------------------------
__global__ void count_kernel(const int* __restrict__ dst, int E, int* __restrict__ cnt) {
  int e = blockIdx.x * blockDim.x + threadIdx.x;
  if (e < E) atomicAdd(&cnt[dst[e]], 1);
}

__global__ __launch_bounds__(1024) void scan_kernel(
    const int* __restrict__ cnt, int n, int* __restrict__ offs, int* __restrict__ cur) {
  __shared__ int sums[1024];
  int t = threadIdx.x;
  int chunk = (n + 1023) / 1024;
  int b = t * chunk;
  int e = min(b + chunk, n);
  int s = 0;
  for (int i = b; i < e; ++i) s += cnt[i];
  sums[t] = s;
  __syncthreads();
  for (int ofs = 1; ofs < 1024; ofs <<= 1) {
    int v = (t >= ofs) ? sums[t - ofs] : 0;
    __syncthreads();
    sums[t] += v;
    __syncthreads();
  }
  int prefix = (t == 0) ? 0 : sums[t - 1];
  for (int i = b; i < e; ++i) {
    offs[i] = prefix;
    cur[i] = prefix;
    prefix += cnt[i];
  }
  if (t == 0) offs[n] = sums[1023];
}

__global__ void fill_kernel(const int* __restrict__ dst, int E,
                            int* __restrict__ cur, int* __restrict__ eid) {
  int e = blockIdx.x * blockDim.x + threadIdx.x;
  if (e < E) {
    int p = atomicAdd(&cur[dst[e]], 1);
    eid[p] = e;
  }
}

// ---------------------------------------------------------------------------
// Aggregation layer 1: one wave per dst node, online softmax, 4 heads.
// Self-loop folded in as initial state. Output: h = elu(agg + b1).
// ---------------------------------------------------------------------------
__global__ __launch_bounds__(256) void agg1_kernel(
    const float* __restrict__ xp, const float* __restrict__ als,
    const float* __restrict__ ald, const int* __restrict__ offs,
    const int* __restrict__ eid, const int* __restrict__ esrc,
    const float* __restrict__ b1, float* __restrict__ hout, int nn) {
  int n = (blockIdx.x * blockDim.x + threadIdx.x) >> 6;
  int lane = threadIdx.x & 63;
  if (n >= nn) return;

  float aldn[4], m[4], d[4], acc[4];
#pragma unroll
  for (int h = 0; h < 4; ++h) aldn[h] = ald[n * 4 + h];
#pragma unroll
  for (int h = 0; h < 4; ++h) {  // self-loop: src == dst
    float a = lrelu(als[n * 4 + h] + aldn[h]);
    m[h] = a;
    d[h] = 1.f;
    acc[h] = xp[(size_t)n * 256 + h * 64 + lane];
  }
  int i0 = offs[n], i1 = offs[n + 1];
  for (int i = i0; i < i1; ++i) {
    int e = eid[i];
    int s = esrc[e];
    const float* xs = xp + (size_t)s * 256 + lane;
#pragma unroll
    for (int h = 0; h < 4; ++h) {
      float a = lrelu(als[s * 4 + h] + aldn[h]);
      float nm = fmaxf(m[h], a);
      float sc = __expf(m[h] - nm);
      float w = __expf(a - nm);
      d[h] = d[h] * sc + w;
      acc[h] = acc[h] * sc + w * xs[h * 64];
      m[h] = nm;
    }
  }
#pragma unroll
  for (int h = 0; h < 4; ++h) {
    float v = acc[h] / d[h] + b1[h * 64 + lane];
    v = v > 0.f ? v : __expf(v) - 1.f;  // elu
    hout[(size_t)n * 256 + h * 64 + lane] = v;
  }
}

// Aggregation layer 2: 1 head, fuse +b2 +skip into final store.
__global__ __launch_bounds__(256) void agg2_kernel(
    const float* __restrict__ xp2, const float* __restrict__ als,
    const float* __restrict__ ald, const int* __restrict__ offs,
    const int* __restrict__ eid, const int* __restrict__ esrc,
    const float* __restrict__ b2, const float* __restrict__ skip,
    float* __restrict__ out, int nn) {
  int n = (blockIdx.x * blockDim.x + threadIdx.x) >> 6;
  int lane = threadIdx.x & 63;
  if (n >= nn) return;

  float aldn = ald[n];
  float a0 = lrelu(als[n] + aldn);
  float m = a0, d = 1.f;
  float acc = xp2[(size_t)n * 64 + lane];
  int i0 = offs[n], i1 = offs[n + 1];
  for (int i = i0; i < i1; ++i) {
    int e = eid[i];
    int s = esrc[e];
    float a = lrelu(als[s] + aldn);
    float nm = fmaxf(m, a);
    float sc = __expf(m - nm);
    float w = __expf(a - nm);
    d = d * sc + w;
    acc = acc * sc + w * xp2[(size_t)s * 64 + lane];
    m = nm;
  }
  out[(size_t)n * 64 + lane] = acc / d + b2[lane] + skip[(size_t)n * 64 + lane];
}

// ---------------------------------------------------------------------------
extern "C" void kernel_launch(void* const* d_in, const int* in_sizes, int n_in,
                              void* d_out, int out_size, void* d_ws, size_t ws_size,
                              hipStream_t stream) {
  const float* x_clean = (const float*)d_in[0];
  const float* x_noised = (const float*)d_in[1];
  const int* esrc = (const int*)d_in[2];
  const int* edst = (const int*)d_in[3];
  const float* W1 = (const float*)d_in[4];
  const float* a_src1 = (const float*)d_in[5];
  const float* a_dst1 = (const float*)d_in[6];
  const float* b1 = (const float*)d_in[7];
  const float* W2 = (const float*)d_in[8];
  const float* a_src2 = (const float*)d_in[9];
  const float* a_dst2 = (const float*)d_in[10];
  const float* b2 = (const float*)d_in[11];
  float* out = (float*)d_out;

  const int N = in_sizes[0] / 256;  // 50000
  const int E = in_sizes[2];        // 800000

  float* ws = (float*)d_ws;
  float* xp1 = ws;                 // N*256
  float* hbuf = xp1 + (size_t)N * 256;  // N*256 (hs, then h)
  float* skip = hbuf + (size_t)N * 256; // N*64
  float* xp2 = skip + (size_t)N * 64;   // N*64
  float* als1 = xp2 + (size_t)N * 64;   // N*4
  float* ald1 = als1 + (size_t)N * 4;   // N*4
  float* als2 = ald1 + (size_t)N * 4;   // N
  float* ald2 = als2 + N;               // N
  int* cnt = (int*)(ald2 + N);          // N
  int* offs = cnt + N;                  // N+1
  int* cur = offs + N + 1;              // N
  int* eid = cur + N;                   // E

  const int gemm_rows = (N + 127) / 128;  // 391
  dim3 block256(256);
  dim3 gemm1_grid(gemm_rows, 4);
  dim3 gemm2_grid(gemm_rows, 1);
  const int wave_grid = (N * 64 + 255) / 256;   // 12500
  const int edge_grid = (E + 255) / 256;

  // xp1 = x_noised @ W1
  hipLaunchKernelGGL((gemm_k256<false, false>), gemm1_grid, block256, 0, stream,
                     x_noised, W1, nullptr, xp1, N, 256);
  // attention logits layer 1
  hipLaunchKernelGGL(al1_kernel, dim3(wave_grid), block256, 0, stream,
                     xp1, a_src1, a_dst1, als1, ald1, N);
  // skip path: hs = relu(x_clean @ W1 + b1);  skip = hs @ W2 + b2
  hipLaunchKernelGGL((gemm_k256<true, true>), gemm1_grid, block256, 0, stream,
                     x_clean, W1, b1, hbuf, N, 256);
  hipLaunchKernelGGL((gemm_k256<true, false>), gemm2_grid, block256, 0, stream,
                     hbuf, W2, b2, skip, N, 64);
  // CSR build over real edges (self-loops handled analytically in agg)
  hipMemsetAsync(cnt, 0, (size_t)N * sizeof(int), stream);
  hipLaunchKernelGGL(count_kernel, dim3(edge_grid), block256, 0, stream, edst, E, cnt);
  hipLaunchKernelGGL(scan_kernel, dim3(1), dim3(1024), 0, stream, cnt, N, offs, cur);
  hipLaunchKernelGGL(fill_kernel, dim3(edge_grid), block256, 0, stream, edst, E, cur, eid);
  // layer-1 aggregation -> h (reuses hbuf, hs already consumed)
  hipLaunchKernelGGL(agg1_kernel, dim3(wave_grid), block256, 0, stream,
                     xp1, als1, ald1, offs, eid, esrc, b1, hbuf, N);
  // xp2 = h @ W2; logits layer 2
  hipLaunchKernelGGL((gemm_k256<false, false>), gemm2_grid, block256, 0, stream,
                     hbuf, W2, nullptr, xp2, N, 64);
  hipLaunchKernelGGL(al2_kernel, dim3(wave_grid), block256, 0, stream,
                     xp2, a_src2, a_dst2, als2, ald2, N);
  // layer-2 aggregation + b2 + skip -> out
  hipLaunchKernelGGL(agg2_kernel, dim3(wave_grid), block256, 0, stream,
                     xp2, als2, ald2, offs, eid, esrc, b2, skip, out, N);
}

// Round 2
// 619.633 us; speedup vs baseline: 1.5735x; 1.5735x over previous
//
#include <hip/hip_runtime.h>
#include <hip/hip_bf16.h>
#include <cstdint>

typedef __bf16 bf16x8 __attribute__((ext_vector_type(8)));
typedef float f32x4 __attribute__((ext_vector_type(4)));

static __device__ __forceinline__ float lrelu(float x) { return x > 0.f ? x : 0.2f * x; }
// bf16 (in low/high ushort of a uint) -> fp32, exact
static __device__ __forceinline__ float bflo(unsigned v) { return __uint_as_float(v << 16); }
static __device__ __forceinline__ float bfhi(unsigned v) { return __uint_as_float(v & 0xffff0000u); }
static __device__ __forceinline__ float bf1(unsigned short v) { return __uint_as_float(((unsigned)v) << 16); }
// fp32 -> bf16 RNE
static __device__ __forceinline__ unsigned short f2bf(float f) {
  unsigned u = __float_as_uint(f);
  u += 0x7fffu + ((u >> 16) & 1u);
  return (unsigned short)(u >> 16);
}

// ---------------------------------------------------------------------------
// bf16 MFMA GEMM: C[M,Nout] = A[M,256] @ W[256,Nout], W given pre-transposed
// (Bt[Nout][256] bf16). K hardcoded 256. BM=128, BN in {128,64}, BK=64.
// 256 threads = 4 waves. BN=128: waves 2x2, each 64x64 (4x4 16-tiles).
// BN=64: waves 4x1, each 32x64 (2x4 16-tiles).
// A is fp32 (converted during staging) or bf16 per AF32.
// ---------------------------------------------------------------------------
template <int BN, bool AF32, bool BIAS, bool RELU, bool OUTBF>
__global__ __launch_bounds__(256) void gemm_mfma(
    const void* __restrict__ Av, const unsigned short* __restrict__ Bt,
    const float* __restrict__ bias, void* __restrict__ Cv, int M, int Nout) {
  constexpr int LDA = 72;  // padded stride (elements): rotates banks by 4/row
  __shared__ __align__(16) unsigned short Al[128 * LDA];
  __shared__ __align__(16) unsigned short Bl[BN * LDA];
  const int t = threadIdx.x;
  const int w = t >> 6, lane = t & 63;
  const int quad = lane >> 4, l15 = lane & 15;
  const int row0 = blockIdx.x * 128;
  const int c0 = blockIdx.y * BN;
  constexpr int WR = (BN == 128) ? 4 : 2;
  const int wrow0 = (BN == 128) ? (w >> 1) * 64 : w * 32;
  const int wcol0 = (BN == 128) ? (w & 1) * 64 : 0;

  f32x4 acc[WR][4];
#pragma unroll
  for (int i = 0; i < WR; ++i)
#pragma unroll
    for (int j = 0; j < 4; ++j) acc[i][j] = (f32x4){0.f, 0.f, 0.f, 0.f};

  for (int k0 = 0; k0 < 256; k0 += 64) {
    // stage A: 128 rows x 64 k = 1024 16B-chunks, 4 per thread
#pragma unroll
    for (int ci = 0; ci < 4; ++ci) {
      int id = ci * 256 + t;
      int r = id >> 3, cq = id & 7;
      int gr = row0 + r;
      uint4 pack = make_uint4(0, 0, 0, 0);
      if (AF32) {
        if (gr < M) {
          const float* ap = (const float*)Av + (size_t)gr * 256 + k0 + cq * 8;
          float4 f0 = *(const float4*)ap;
          float4 f1 = *(const float4*)(ap + 4);
          pack.x = (unsigned)f2bf(f0.x) | ((unsigned)f2bf(f0.y) << 16);
          pack.y = (unsigned)f2bf(f0.z) | ((unsigned)f2bf(f0.w) << 16);
          pack.z = (unsigned)f2bf(f1.x) | ((unsigned)f2bf(f1.y) << 16);
          pack.w = (unsigned)f2bf(f1.z) | ((unsigned)f2bf(f1.w) << 16);
        }
      } else {
        if (gr < M)
          pack = *(const uint4*)((const unsigned short*)Av + (size_t)gr * 256 + k0 + cq * 8);
      }
      *(uint4*)&Al[r * LDA + cq * 8] = pack;
    }
    // stage B: BN rows x 64 k
#pragma unroll
    for (int ci = 0; ci < BN / 32; ++ci) {
      int id = ci * 256 + t;
      int r = id >> 3, cq = id & 7;
      *(uint4*)&Bl[r * LDA + cq * 8] =
          *(const uint4*)(Bt + (size_t)(c0 + r) * 256 + k0 + cq * 8);
    }
    __syncthreads();
#pragma unroll
    for (int ks = 0; ks < 64; ks += 32) {
      bf16x8 af[WR], bfr[4];
#pragma unroll
      for (int i = 0; i < WR; ++i)
        af[i] = *(const bf16x8*)&Al[(wrow0 + i * 16 + l15) * LDA + ks + quad * 8];
#pragma unroll
      for (int j = 0; j < 4; ++j)
        bfr[j] = *(const bf16x8*)&Bl[(wcol0 + j * 16 + l15) * LDA + ks + quad * 8];
#pragma unroll
      for (int i = 0; i < WR; ++i)
#pragma unroll
        for (int j = 0; j < 4; ++j)
          acc[i][j] = __builtin_amdgcn_mfma_f32_16x16x32_bf16(af[i], bfr[j], acc[i][j], 0, 0, 0);
    }
    __syncthreads();
  }
  // epilogue: C/D layout col=lane&15, row=quad*4+reg
#pragma unroll
  for (int i = 0; i < WR; ++i) {
#pragma unroll
    for (int j = 0; j < 4; ++j) {
      int col = c0 + wcol0 + j * 16 + l15;
      float bv = BIAS ? bias[col] : 0.f;
#pragma unroll
      for (int r = 0; r < 4; ++r) {
        int row = row0 + wrow0 + i * 16 + quad * 4 + r;
        if (row < M) {
          float v = acc[i][j][r] + bv;
          if (RELU) v = fmaxf(v, 0.f);
          if (OUTBF)
            ((unsigned short*)Cv)[(size_t)row * Nout + col] = f2bf(v);
          else
            ((float*)Cv)[(size_t)row * Nout + col] = v;
        }
      }
    }
  }
}

// transpose-convert W[K][Nout] fp32 -> Wt[Nout][K=256] bf16
__global__ void trcvt_kernel(const float* __restrict__ in, unsigned short* __restrict__ out,
                             int Nout) {
  int id = blockIdx.x * blockDim.x + threadIdx.x;  // over Nout*256
  if (id < Nout * 256) {
    int k = id & 255, n = id >> 8;
    out[id] = f2bf(in[k * Nout + n]);
  }
}

// ---------------------------------------------------------------------------
// al1: wave per node; lane holds channels 4l..4l+3 (head = l>>4); reduce in
// 16-lane groups -> als/ald [N,4]
// ---------------------------------------------------------------------------
__global__ __launch_bounds__(256) void al1_kernel(
    const unsigned short* __restrict__ xp, const float* __restrict__ asrc,
    const float* __restrict__ adst, float* __restrict__ als, float* __restrict__ ald, int nn) {
  int wid = (blockIdx.x * blockDim.x + threadIdx.x) >> 6;
  int lane = threadIdx.x & 63;
  if (wid >= nn) return;
  uint2 v = *(const uint2*)(xp + (size_t)wid * 256 + lane * 4);
  float4 as4 = *(const float4*)(asrc + lane * 4);
  float4 ad4 = *(const float4*)(adst + lane * 4);
  float x0 = bflo(v.x), x1 = bfhi(v.x), x2 = bflo(v.y), x3 = bfhi(v.y);
  float ps = x0 * as4.x + x1 * as4.y + x2 * as4.z + x3 * as4.w;
  float pd = x0 * ad4.x + x1 * ad4.y + x2 * ad4.z + x3 * ad4.w;
#pragma unroll
  for (int o = 8; o; o >>= 1) {
    ps += __shfl_xor(ps, o, 64);
    pd += __shfl_xor(pd, o, 64);
  }
  if ((lane & 15) == 0) {
    als[wid * 4 + (lane >> 4)] = ps;
    ald[wid * 4 + (lane >> 4)] = pd;
  }
}

__global__ __launch_bounds__(256) void al2_kernel(
    const unsigned short* __restrict__ xp2, const float* __restrict__ asrc,
    const float* __restrict__ adst, float* __restrict__ als, float* __restrict__ ald, int nn) {
  int wid = (blockIdx.x * blockDim.x + threadIdx.x) >> 6;
  int lane = threadIdx.x & 63;
  if (wid >= nn) return;
  float x = bf1(xp2[(size_t)wid * 64 + lane]);
  float ps = x * asrc[lane];
  float pd = x * adst[lane];
#pragma unroll
  for (int o = 32; o; o >>= 1) {
    ps += __shfl_xor(ps, o, 64);
    pd += __shfl_xor(pd, o, 64);
  }
  if (lane == 0) {
    als[wid] = ps;
    ald[wid] = pd;
  }
}

// ---------------------------------------------------------------------------
// CSR build (stores src id directly -> no eid indirection in agg)
// ---------------------------------------------------------------------------
__global__ void count_kernel(const int* __restrict__ dst, int E, int* __restrict__ cnt) {
  int e = blockIdx.x * blockDim.x + threadIdx.x;
  if (e < E) atomicAdd(&cnt[dst[e]], 1);
}

__global__ __launch_bounds__(1024) void scan_kernel(
    const int* __restrict__ cnt, int n, int* __restrict__ offs, int* __restrict__ cur) {
  __shared__ int sums[1024];
  int t = threadIdx.x;
  int chunk = (n + 1023) / 1024;
  int b = t * chunk;
  int e = min(b + chunk, n);
  int s = 0;
  for (int i = b; i < e; ++i) s += cnt[i];
  sums[t] = s;
  __syncthreads();
  for (int ofs = 1; ofs < 1024; ofs <<= 1) {
    int v = (t >= ofs) ? sums[t - ofs] : 0;
    __syncthreads();
    sums[t] += v;
    __syncthreads();
  }
  int prefix = (t == 0) ? 0 : sums[t - 1];
  for (int i = b; i < e; ++i) {
    offs[i] = prefix;
    cur[i] = prefix;
    prefix += cnt[i];
  }
  if (t == 0) offs[n] = sums[1023];
}

__global__ void fill_kernel(const int* __restrict__ dst, const int* __restrict__ src, int E,
                            int* __restrict__ cur, int* __restrict__ csrc) {
  int e = blockIdx.x * blockDim.x + threadIdx.x;
  if (e < E) {
    int p = atomicAdd(&cur[dst[e]], 1);
    csrc[p] = src[e];
  }
}

// ---------------------------------------------------------------------------
// agg1: wave per dst node; lane owns channels 4l..4l+3 (single head l>>4).
// Online softmax, self-loop as initial state. out = elu(agg + b1) in bf16.
// ---------------------------------------------------------------------------
__global__ __launch_bounds__(256) void agg1_kernel(
    const unsigned short* __restrict__ xp, const float* __restrict__ als,
    const float* __restrict__ ald, const int* __restrict__ offs,
    const int* __restrict__ csrc, const float* __restrict__ b1,
    unsigned short* __restrict__ hout, int nn) {
  int n = (blockIdx.x * blockDim.x + threadIdx.x) >> 6;
  int lane = threadIdx.x & 63;
  if (n >= nn) return;
  int h = lane >> 4;
  float aldn = ald[n * 4 + h];
  float m = lrelu(als[n * 4 + h] + aldn), d = 1.f;
  uint2 v = *(const uint2*)(xp + (size_t)n * 256 + lane * 4);
  float a0 = bflo(v.x), a1 = bfhi(v.x), a2 = bflo(v.y), a3 = bfhi(v.y);
  int i0 = offs[n], i1 = offs[n + 1];
  for (int i = i0; i < i1; ++i) {
    int s = csrc[i];
    uint2 u = *(const uint2*)(xp + (size_t)s * 256 + lane * 4);
    float a = lrelu(als[s * 4 + h] + aldn);
    float nm = fmaxf(m, a);
    float sc = __expf(m - nm);
    float wgt = __expf(a - nm);
    d = d * sc + wgt;
    a0 = a0 * sc + wgt * bflo(u.x);
    a1 = a1 * sc + wgt * bfhi(u.x);
    a2 = a2 * sc + wgt * bflo(u.y);
    a3 = a3 * sc + wgt * bfhi(u.y);
    m = nm;
  }
  float inv = 1.f / d;
  float4 bb = *(const float4*)(b1 + lane * 4);
  float o0 = a0 * inv + bb.x, o1 = a1 * inv + bb.y;
  float o2 = a2 * inv + bb.z, o3 = a3 * inv + bb.w;
  o0 = o0 > 0.f ? o0 : __expf(o0) - 1.f;
  o1 = o1 > 0.f ? o1 : __expf(o1) - 1.f;
  o2 = o2 > 0.f ? o2 : __expf(o2) - 1.f;
  o3 = o3 > 0.f ? o3 : __expf(o3) - 1.f;
  uint2 p;
  p.x = (unsigned)f2bf(o0) | ((unsigned)f2bf(o1) << 16);
  p.y = (unsigned)f2bf(o2) | ((unsigned)f2bf(o3) << 16);
  *(uint2*)(hout + (size_t)n * 256 + lane * 4) = p;
}

// agg2: 1 head; lane owns 1 channel; fuse +b2 +skip into final store (fp32).
__global__ __launch_bounds__(256) void agg2_kernel(
    const unsigned short* __restrict__ xp2, const float* __restrict__ als,
    const float* __restrict__ ald, const int* __restrict__ offs,
    const int* __restrict__ csrc, const float* __restrict__ b2,
    const float* __restrict__ skip, float* __restrict__ out, int nn) {
  int n = (blockIdx.x * blockDim.x + threadIdx.x) >> 6;
  int lane = threadIdx.x & 63;
  if (n >= nn) return;
  float aldn = ald[n];
  float m = lrelu(als[n] + aldn), d = 1.f;
  float acc = bf1(xp2[(size_t)n * 64 + lane]);
  int i0 = offs[n], i1 = offs[n + 1];
  for (int i = i0; i < i1; ++i) {
    int s = csrc[i];
    float x = bf1(xp2[(size_t)s * 64 + lane]);
    float a = lrelu(als[s] + aldn);
    float nm = fmaxf(m, a);
    float sc = __expf(m - nm);
    float wgt = __expf(a - nm);
    d = d * sc + wgt;
    acc = acc * sc + wgt * x;
    m = nm;
  }
  out[(size_t)n * 64 + lane] = acc / d + b2[lane] + skip[(size_t)n * 64 + lane];
}

// ---------------------------------------------------------------------------
extern "C" void kernel_launch(void* const* d_in, const int* in_sizes, int n_in,
                              void* d_out, int out_size, void* d_ws, size_t ws_size,
                              hipStream_t stream) {
  const float* x_clean = (const float*)d_in[0];
  const float* x_noised = (const float*)d_in[1];
  const int* esrc = (const int*)d_in[2];
  const int* edst = (const int*)d_in[3];
  const float* W1 = (const float*)d_in[4];
  const float* a_src1 = (const float*)d_in[5];
  const float* a_dst1 = (const float*)d_in[6];
  const float* b1 = (const float*)d_in[7];
  const float* W2 = (const float*)d_in[8];
  const float* a_src2 = (const float*)d_in[9];
  const float* a_dst2 = (const float*)d_in[10];
  const float* b2 = (const float*)d_in[11];
  float* out = (float*)d_out;

  const int N = in_sizes[0] / 256;  // 50000
  const int E = in_sizes[2];        // 800000

  unsigned short* W1t = (unsigned short*)d_ws;      // 256*256
  unsigned short* W2t = W1t + 65536;                // 64*256
  unsigned short* xp1 = W2t + 16384;                // N*256 bf16
  unsigned short* hs = xp1 + (size_t)N * 256;       // N*256 bf16 (hs, then h)
  unsigned short* xp2 = hs + (size_t)N * 256;       // N*64 bf16
  float* skip = (float*)(xp2 + (size_t)N * 64);     // N*64 f32
  float* als1 = skip + (size_t)N * 64;              // N*4
  float* ald1 = als1 + (size_t)N * 4;               // N*4
  float* als2 = ald1 + (size_t)N * 4;               // N
  float* ald2 = als2 + N;                           // N
  int* cnt = (int*)(ald2 + N);                      // N
  int* offs = cnt + N;                              // N+1
  int* cur = offs + N + 1;                          // N
  int* csrc = cur + N;                              // E

  const int gemm_rows = (N + 127) / 128;  // 391
  dim3 block256(256);
  const int wave_grid = (N * 64 + 255) / 256;  // 12500
  const int edge_grid = (E + 255) / 256;

  // weight transpose+convert (tiny)
  hipLaunchKernelGGL(trcvt_kernel, dim3(256), block256, 0, stream, W1, W1t, 256);
  hipLaunchKernelGGL(trcvt_kernel, dim3(64), block256, 0, stream, W2, W2t, 64);
  // xp1 = x_noised @ W1 (bf16 out)
  hipLaunchKernelGGL((gemm_mfma<128, true, false, false, true>), dim3(gemm_rows, 2), block256,
                     0, stream, x_noised, W1t, nullptr, xp1, N, 256);
  // hs = relu(x_clean @ W1 + b1) (bf16 out)
  hipLaunchKernelGGL((gemm_mfma<128, true, true, true, true>), dim3(gemm_rows, 2), block256,
                     0, stream, x_clean, W1t, b1, hs, N, 256);
  // skip = hs @ W2 + b2 (fp32 out)
  hipLaunchKernelGGL((gemm_mfma<64, false, true, false, false>), dim3(gemm_rows, 1), block256,
                     0, stream, hs, W2t, b2, skip, N, 64);
  // attention logits layer 1
  hipLaunchKernelGGL(al1_kernel, dim3(wave_grid), block256, 0, stream,
                     xp1, a_src1, a_dst1, als1, ald1, N);
  // CSR build
  hipMemsetAsync(cnt, 0, (size_t)N * sizeof(int), stream);
  hipLaunchKernelGGL(count_kernel, dim3(edge_grid), block256, 0, stream, edst, E, cnt);
  hipLaunchKernelGGL(scan_kernel, dim3(1), dim3(1024), 0, stream, cnt, N, offs, cur);
  hipLaunchKernelGGL(fill_kernel, dim3(edge_grid), block256, 0, stream, edst, esrc, E, cur, csrc);
  // layer-1 aggregation -> h (reuses hs buffer; hs consumed by skip gemm above)
  hipLaunchKernelGGL(agg1_kernel, dim3(wave_grid), block256, 0, stream,
                     xp1, als1, ald1, offs, csrc, b1, hs, N);
  // xp2 = h @ W2 (bf16 out)
  hipLaunchKernelGGL((gemm_mfma<64, false, false, false, true>), dim3(gemm_rows, 1), block256,
                     0, stream, hs, W2t, nullptr, xp2, N, 64);
  // logits layer 2
  hipLaunchKernelGGL(al2_kernel, dim3(wave_grid), block256, 0, stream,
                     xp2, a_src2, a_dst2, als2, ald2, N);
  // layer-2 aggregation + b2 + skip -> out
  hipLaunchKernelGGL(agg2_kernel, dim3(wave_grid), block256, 0, stream,
                     xp2, als2, ald2, offs, csrc, b2, skip, out, N);
}

// Round 3
// 516.007 us; speedup vs baseline: 1.8895x; 1.2008x over previous
//
#include <hip/hip_runtime.h>
#include <hip/hip_bf16.h>
#include <cstdint>

typedef __bf16 bf16x8 __attribute__((ext_vector_type(8)));
typedef float f32x4 __attribute__((ext_vector_type(4)));

static __device__ __forceinline__ float lrelu(float x) { return x > 0.f ? x : 0.2f * x; }
// bf16 (in low/high ushort of a uint) -> fp32, exact
static __device__ __forceinline__ float bflo(unsigned v) { return __uint_as_float(v << 16); }
static __device__ __forceinline__ float bfhi(unsigned v) { return __uint_as_float(v & 0xffff0000u); }
static __device__ __forceinline__ float bf1(unsigned short v) { return __uint_as_float(((unsigned)v) << 16); }
// fp32 -> bf16 RNE
static __device__ __forceinline__ unsigned short f2bf(float f) {
  unsigned u = __float_as_uint(f);
  u += 0x7fffu + ((u >> 16) & 1u);
  return (unsigned short)(u >> 16);
}

// ---------------------------------------------------------------------------
// bf16 MFMA GEMM: C[M,Nout] = A[M,256] @ W[256,Nout], W given pre-transposed
// (Bt[Nout][256] bf16). K hardcoded 256. BM=128, BN in {128,64}, BK=64.
// ---------------------------------------------------------------------------
template <int BN, bool AF32, bool BIAS, bool RELU, bool OUTBF>
__global__ __launch_bounds__(256) void gemm_mfma(
    const void* __restrict__ Av, const unsigned short* __restrict__ Bt,
    const float* __restrict__ bias, void* __restrict__ Cv, int M, int Nout) {
  constexpr int LDA = 72;  // padded stride (elements)
  __shared__ __align__(16) unsigned short Al[128 * LDA];
  __shared__ __align__(16) unsigned short Bl[BN * LDA];
  const int t = threadIdx.x;
  const int w = t >> 6, lane = t & 63;
  const int quad = lane >> 4, l15 = lane & 15;
  const int row0 = blockIdx.x * 128;
  const int c0 = blockIdx.y * BN;
  constexpr int WR = (BN == 128) ? 4 : 2;
  const int wrow0 = (BN == 128) ? (w >> 1) * 64 : w * 32;
  const int wcol0 = (BN == 128) ? (w & 1) * 64 : 0;

  f32x4 acc[WR][4];
#pragma unroll
  for (int i = 0; i < WR; ++i)
#pragma unroll
    for (int j = 0; j < 4; ++j) acc[i][j] = (f32x4){0.f, 0.f, 0.f, 0.f};

  for (int k0 = 0; k0 < 256; k0 += 64) {
#pragma unroll
    for (int ci = 0; ci < 4; ++ci) {
      int id = ci * 256 + t;
      int r = id >> 3, cq = id & 7;
      int gr = row0 + r;
      uint4 pack = make_uint4(0, 0, 0, 0);
      if (AF32) {
        if (gr < M) {
          const float* ap = (const float*)Av + (size_t)gr * 256 + k0 + cq * 8;
          float4 f0 = *(const float4*)ap;
          float4 f1 = *(const float4*)(ap + 4);
          pack.x = (unsigned)f2bf(f0.x) | ((unsigned)f2bf(f0.y) << 16);
          pack.y = (unsigned)f2bf(f0.z) | ((unsigned)f2bf(f0.w) << 16);
          pack.z = (unsigned)f2bf(f1.x) | ((unsigned)f2bf(f1.y) << 16);
          pack.w = (unsigned)f2bf(f1.z) | ((unsigned)f2bf(f1.w) << 16);
        }
      } else {
        if (gr < M)
          pack = *(const uint4*)((const unsigned short*)Av + (size_t)gr * 256 + k0 + cq * 8);
      }
      *(uint4*)&Al[r * LDA + cq * 8] = pack;
    }
#pragma unroll
    for (int ci = 0; ci < BN / 32; ++ci) {
      int id = ci * 256 + t;
      int r = id >> 3, cq = id & 7;
      *(uint4*)&Bl[r * LDA + cq * 8] =
          *(const uint4*)(Bt + (size_t)(c0 + r) * 256 + k0 + cq * 8);
    }
    __syncthreads();
#pragma unroll
    for (int ks = 0; ks < 64; ks += 32) {
      bf16x8 af[WR], bfr[4];
#pragma unroll
      for (int i = 0; i < WR; ++i)
        af[i] = *(const bf16x8*)&Al[(wrow0 + i * 16 + l15) * LDA + ks + quad * 8];
#pragma unroll
      for (int j = 0; j < 4; ++j)
        bfr[j] = *(const bf16x8*)&Bl[(wcol0 + j * 16 + l15) * LDA + ks + quad * 8];
#pragma unroll
      for (int i = 0; i < WR; ++i)
#pragma unroll
        for (int j = 0; j < 4; ++j)
          acc[i][j] = __builtin_amdgcn_mfma_f32_16x16x32_bf16(af[i], bfr[j], acc[i][j], 0, 0, 0);
    }
    __syncthreads();
  }
#pragma unroll
  for (int i = 0; i < WR; ++i) {
#pragma unroll
    for (int j = 0; j < 4; ++j) {
      int col = c0 + wcol0 + j * 16 + l15;
      float bv = BIAS ? bias[col] : 0.f;
#pragma unroll
      for (int r = 0; r < 4; ++r) {
        int row = row0 + wrow0 + i * 16 + quad * 4 + r;
        if (row < M) {
          float v = acc[i][j][r] + bv;
          if (RELU) v = fmaxf(v, 0.f);
          if (OUTBF)
            ((unsigned short*)Cv)[(size_t)row * Nout + col] = f2bf(v);
          else
            ((float*)Cv)[(size_t)row * Nout + col] = v;
        }
      }
    }
  }
}

// transpose-convert W[K][Nout] fp32 -> Wt[Nout][K=256] bf16
__global__ void trcvt_kernel(const float* __restrict__ in, unsigned short* __restrict__ out,
                             int Nout) {
  int id = blockIdx.x * blockDim.x + threadIdx.x;
  if (id < Nout * 256) {
    int k = id & 255, n = id >> 8;
    out[id] = f2bf(in[k * Nout + n]);
  }
}

// ---------------------------------------------------------------------------
// attention logits
// ---------------------------------------------------------------------------
__global__ __launch_bounds__(256) void al1_kernel(
    const unsigned short* __restrict__ xp, const float* __restrict__ asrc,
    const float* __restrict__ adst, float* __restrict__ als, float* __restrict__ ald, int nn) {
  int wid = (blockIdx.x * blockDim.x + threadIdx.x) >> 6;
  int lane = threadIdx.x & 63;
  if (wid >= nn) return;
  uint2 v = *(const uint2*)(xp + (size_t)wid * 256 + lane * 4);
  float4 as4 = *(const float4*)(asrc + lane * 4);
  float4 ad4 = *(const float4*)(adst + lane * 4);
  float x0 = bflo(v.x), x1 = bfhi(v.x), x2 = bflo(v.y), x3 = bfhi(v.y);
  float ps = x0 * as4.x + x1 * as4.y + x2 * as4.z + x3 * as4.w;
  float pd = x0 * ad4.x + x1 * ad4.y + x2 * ad4.z + x3 * ad4.w;
#pragma unroll
  for (int o = 8; o; o >>= 1) {
    ps += __shfl_xor(ps, o, 64);
    pd += __shfl_xor(pd, o, 64);
  }
  if ((lane & 15) == 0) {
    als[wid * 4 + (lane >> 4)] = ps;
    ald[wid * 4 + (lane >> 4)] = pd;
  }
}

__global__ __launch_bounds__(256) void al2_kernel(
    const unsigned short* __restrict__ xp2, const float* __restrict__ asrc,
    const float* __restrict__ adst, float* __restrict__ als, float* __restrict__ ald, int nn) {
  int wid = (blockIdx.x * blockDim.x + threadIdx.x) >> 6;
  int lane = threadIdx.x & 63;
  if (wid >= nn) return;
  float x = bf1(xp2[(size_t)wid * 64 + lane]);
  float ps = x * asrc[lane];
  float pd = x * adst[lane];
#pragma unroll
  for (int o = 32; o; o >>= 1) {
    ps += __shfl_xor(ps, o, 64);
    pd += __shfl_xor(pd, o, 64);
  }
  if (lane == 0) {
    als[wid] = ps;
    ald[wid] = pd;
  }
}

// ---------------------------------------------------------------------------
// CSR build — hierarchical scan (3 tiny parallel kernels)
// ---------------------------------------------------------------------------
__global__ void count_kernel(const int* __restrict__ dst, int E, int* __restrict__ cnt) {
  int e = blockIdx.x * blockDim.x + threadIdx.x;
  if (e < E) atomicAdd(&cnt[dst[e]], 1);
}

// block b: 1024 elements (256 thr x 4), local exclusive scan -> offs, total -> bsum[b]
__global__ __launch_bounds__(256) void scan_blocks(
    const int* __restrict__ cnt, int n, int* __restrict__ offs, int* __restrict__ bsum) {
  int t = threadIdx.x;
  int base = blockIdx.x * 1024 + t * 4;
  int4 v = make_int4(0, 0, 0, 0);
  if (base + 3 < n) {
    v = *(const int4*)(cnt + base);
  } else {
    if (base + 0 < n) v.x = cnt[base + 0];
    if (base + 1 < n) v.y = cnt[base + 1];
    if (base + 2 < n) v.z = cnt[base + 2];
  }
  int s = v.x + v.y + v.z + v.w;
  int lane = t & 63, w = t >> 6;
  int sc = s;  // inclusive wave scan
#pragma unroll
  for (int o = 1; o < 64; o <<= 1) {
    int u = __shfl_up(sc, o, 64);
    if (lane >= o) sc += u;
  }
  __shared__ int wsum[4];
  if (lane == 63) wsum[w] = sc;
  __syncthreads();
  int woff = 0;
#pragma unroll
  for (int i = 0; i < 4; ++i)
    if (i < w) woff += wsum[i];
  int excl = woff + sc - s;
  int o0 = excl, o1 = o0 + v.x, o2 = o1 + v.y, o3 = o2 + v.z;
  if (base + 3 < n) {
    *(int4*)(offs + base) = make_int4(o0, o1, o2, o3);
  } else {
    if (base + 0 < n) offs[base + 0] = o0;
    if (base + 1 < n) offs[base + 1] = o1;
    if (base + 2 < n) offs[base + 2] = o2;
  }
  if (t == 255) bsum[blockIdx.x] = woff + sc;
}

// single wave scans block sums (nb <= 64)
__global__ void scan_top(const int* __restrict__ bsum, int nb, int* __restrict__ boff,
                         int* __restrict__ offs, int n) {
  int lane = threadIdx.x;
  int s = (lane < nb) ? bsum[lane] : 0;
  int sc = s;
#pragma unroll
  for (int o = 1; o < 64; o <<= 1) {
    int u = __shfl_up(sc, o, 64);
    if (lane >= o) sc += u;
  }
  if (lane < nb) boff[lane] = sc - s;
  if (lane == 63) offs[n] = sc;
}

__global__ __launch_bounds__(256) void scan_add(
    int* __restrict__ offs, int* __restrict__ cur, const int* __restrict__ boff, int n) {
  int t = threadIdx.x;
  int base = blockIdx.x * 1024 + t * 4;
  int b = boff[blockIdx.x];
  if (base + 3 < n) {
    int4 v = *(const int4*)(offs + base);
    v.x += b; v.y += b; v.z += b; v.w += b;
    *(int4*)(offs + base) = v;
    *(int4*)(cur + base) = v;
  } else {
    for (int i = 0; i < 4; ++i)
      if (base + i < n) {
        int v = offs[base + i] + b;
        offs[base + i] = v;
        cur[base + i] = v;
      }
  }
}

__global__ void fill_kernel(const int* __restrict__ dst, const int* __restrict__ src, int E,
                            int* __restrict__ cur, int* __restrict__ csrc) {
  int e = blockIdx.x * blockDim.x + threadIdx.x;
  if (e < E) {
    int p = atomicAdd(&cur[dst[e]], 1);
    csrc[p] = src[e];
  }
}

// ---------------------------------------------------------------------------
// agg1: wave per dst node; lane owns channels 4l..4l+3 (head l>>4).
// ---------------------------------------------------------------------------
__global__ __launch_bounds__(256) void agg1_kernel(
    const unsigned short* __restrict__ xp, const float* __restrict__ als,
    const float* __restrict__ ald, const int* __restrict__ offs,
    const int* __restrict__ csrc, const float* __restrict__ b1,
    unsigned short* __restrict__ hout, int nn) {
  int n = (blockIdx.x * blockDim.x + threadIdx.x) >> 6;
  int lane = threadIdx.x & 63;
  if (n >= nn) return;
  int h = lane >> 4;
  float aldn = ald[n * 4 + h];
  float m = lrelu(als[n * 4 + h] + aldn), d = 1.f;
  uint2 v = *(const uint2*)(xp + (size_t)n * 256 + lane * 4);
  float a0 = bflo(v.x), a1 = bfhi(v.x), a2 = bflo(v.y), a3 = bfhi(v.y);
  int i0 = offs[n], i1 = offs[n + 1];
  for (int i = i0; i < i1; ++i) {
    int s = csrc[i];
    uint2 u = *(const uint2*)(xp + (size_t)s * 256 + lane * 4);
    float a = lrelu(als[s * 4 + h] + aldn);
    float nm = fmaxf(m, a);
    float sc = __expf(m - nm);
    float wgt = __expf(a - nm);
    d = d * sc + wgt;
    a0 = a0 * sc + wgt * bflo(u.x);
    a1 = a1 * sc + wgt * bfhi(u.x);
    a2 = a2 * sc + wgt * bflo(u.y);
    a3 = a3 * sc + wgt * bfhi(u.y);
    m = nm;
  }
  float inv = 1.f / d;
  float4 bb = *(const float4*)(b1 + lane * 4);
  float o0 = a0 * inv + bb.x, o1 = a1 * inv + bb.y;
  float o2 = a2 * inv + bb.z, o3 = a3 * inv + bb.w;
  o0 = o0 > 0.f ? o0 : __expf(o0) - 1.f;
  o1 = o1 > 0.f ? o1 : __expf(o1) - 1.f;
  o2 = o2 > 0.f ? o2 : __expf(o2) - 1.f;
  o3 = o3 > 0.f ? o3 : __expf(o3) - 1.f;
  uint2 p;
  p.x = (unsigned)f2bf(o0) | ((unsigned)f2bf(o1) << 16);
  p.y = (unsigned)f2bf(o2) | ((unsigned)f2bf(o3) << 16);
  *(uint2*)(hout + (size_t)n * 256 + lane * 4) = p;
}

// agg2: 1 head; lane owns 1 channel; fuse +b2 +skip into final store (fp32).
__global__ __launch_bounds__(256) void agg2_kernel(
    const unsigned short* __restrict__ xp2, const float* __restrict__ als,
    const float* __restrict__ ald, const int* __restrict__ offs,
    const int* __restrict__ csrc, const float* __restrict__ b2,
    const float* __restrict__ skip, float* __restrict__ out, int nn) {
  int n = (blockIdx.x * blockDim.x + threadIdx.x) >> 6;
  int lane = threadIdx.x & 63;
  if (n >= nn) return;
  float aldn = ald[n];
  float m = lrelu(als[n] + aldn), d = 1.f;
  float acc = bf1(xp2[(size_t)n * 64 + lane]);
  int i0 = offs[n], i1 = offs[n + 1];
  for (int i = i0; i < i1; ++i) {
    int s = csrc[i];
    float x = bf1(xp2[(size_t)s * 64 + lane]);
    float a = lrelu(als[s] + aldn);
    float nm = fmaxf(m, a);
    float sc = __expf(m - nm);
    float wgt = __expf(a - nm);
    d = d * sc + wgt;
    acc = acc * sc + wgt * x;
    m = nm;
  }
  out[(size_t)n * 64 + lane] = acc / d + b2[lane] + skip[(size_t)n * 64 + lane];
}

// ---------------------------------------------------------------------------
extern "C" void kernel_launch(void* const* d_in, const int* in_sizes, int n_in,
                              void* d_out, int out_size, void* d_ws, size_t ws_size,
                              hipStream_t stream) {
  const float* x_clean = (const float*)d_in[0];
  const float* x_noised = (const float*)d_in[1];
  const int* esrc = (const int*)d_in[2];
  const int* edst = (const int*)d_in[3];
  const float* W1 = (const float*)d_in[4];
  const float* a_src1 = (const float*)d_in[5];
  const float* a_dst1 = (const float*)d_in[6];
  const float* b1 = (const float*)d_in[7];
  const float* W2 = (const float*)d_in[8];
  const float* a_src2 = (const float*)d_in[9];
  const float* a_dst2 = (const float*)d_in[10];
  const float* b2 = (const float*)d_in[11];
  float* out = (float*)d_out;

  const int N = in_sizes[0] / 256;  // 50000
  const int E = in_sizes[2];        // 800000

  unsigned short* W1t = (unsigned short*)d_ws;      // 256*256
  unsigned short* W2t = W1t + 65536;                // 64*256
  unsigned short* xp1 = W2t + 16384;                // N*256 bf16
  unsigned short* hs = xp1 + (size_t)N * 256;       // N*256 bf16 (hs, then h)
  unsigned short* xp2 = hs + (size_t)N * 256;       // N*64 bf16
  float* skip = (float*)(xp2 + (size_t)N * 64);     // N*64 f32
  float* als1 = skip + (size_t)N * 64;              // N*4
  float* ald1 = als1 + (size_t)N * 4;               // N*4
  float* als2 = ald1 + (size_t)N * 4;               // N
  float* ald2 = als2 + N;                           // N
  int* cnt = (int*)(ald2 + N);                      // N
  int* offs = cnt + N;                              // N+1
  int* cur = offs + N + 1;                          // N
  int* csrc = cur + N;                              // E
  int* bsum = csrc + E;                             // <=64
  int* boff = bsum + 64;                            // <=64

  const int gemm_rows = (N + 127) / 128;  // 391
  dim3 block256(256);
  const int wave_grid = (N * 64 + 255) / 256;  // 12500
  const int edge_grid = (E + 255) / 256;
  const int nb = (N + 1023) / 1024;  // 49 scan blocks

  hipLaunchKernelGGL(trcvt_kernel, dim3(256), block256, 0, stream, W1, W1t, 256);
  hipLaunchKernelGGL(trcvt_kernel, dim3(64), block256, 0, stream, W2, W2t, 64);
  // xp1 = x_noised @ W1 (bf16 out)
  hipLaunchKernelGGL((gemm_mfma<128, true, false, false, true>), dim3(gemm_rows, 2), block256,
                     0, stream, x_noised, W1t, nullptr, xp1, N, 256);
  // hs = relu(x_clean @ W1 + b1) (bf16 out)
  hipLaunchKernelGGL((gemm_mfma<128, true, true, true, true>), dim3(gemm_rows, 2), block256,
                     0, stream, x_clean, W1t, b1, hs, N, 256);
  // skip = hs @ W2 + b2 (fp32 out)
  hipLaunchKernelGGL((gemm_mfma<64, false, true, false, false>), dim3(gemm_rows, 1), block256,
                     0, stream, hs, W2t, b2, skip, N, 64);
  // attention logits layer 1
  hipLaunchKernelGGL(al1_kernel, dim3(wave_grid), block256, 0, stream,
                     xp1, a_src1, a_dst1, als1, ald1, N);
  // CSR build
  hipMemsetAsync(cnt, 0, (size_t)N * sizeof(int), stream);
  hipLaunchKernelGGL(count_kernel, dim3(edge_grid), block256, 0, stream, edst, E, cnt);
  hipLaunchKernelGGL(scan_blocks, dim3(nb), block256, 0, stream, cnt, N, offs, bsum);
  hipLaunchKernelGGL(scan_top, dim3(1), dim3(64), 0, stream, bsum, nb, boff, offs, N);
  hipLaunchKernelGGL(scan_add, dim3(nb), block256, 0, stream, offs, cur, boff, N);
  hipLaunchKernelGGL(fill_kernel, dim3(edge_grid), block256, 0, stream, edst, esrc, E, cur, csrc);
  // layer-1 aggregation -> h
  hipLaunchKernelGGL(agg1_kernel, dim3(wave_grid), block256, 0, stream,
                     xp1, als1, ald1, offs, csrc, b1, hs, N);
  // xp2 = h @ W2 (bf16 out)
  hipLaunchKernelGGL((gemm_mfma<64, false, false, false, true>), dim3(gemm_rows, 1), block256,
                     0, stream, hs, W2t, nullptr, xp2, N, 64);
  // logits layer 2
  hipLaunchKernelGGL(al2_kernel, dim3(wave_grid), block256, 0, stream,
                     xp2, a_src2, a_dst2, als2, ald2, N);
  // layer-2 aggregation + b2 + skip -> out
  hipLaunchKernelGGL(agg2_kernel, dim3(wave_grid), block256, 0, stream,
                     xp2, als2, ald2, offs, csrc, b2, skip, out, N);
}

// Round 4
// 482.960 us; speedup vs baseline: 2.0188x; 1.0684x over previous
//
#include <hip/hip_runtime.h>
#include <hip/hip_bf16.h>
#include <cstdint>

typedef __bf16 bf16x8 __attribute__((ext_vector_type(8)));
typedef float f32x4 __attribute__((ext_vector_type(4)));

static __device__ __forceinline__ float lrelu(float x) { return x > 0.f ? x : 0.2f * x; }
static __device__ __forceinline__ float bflo(unsigned v) { return __uint_as_float(v << 16); }
static __device__ __forceinline__ float bfhi(unsigned v) { return __uint_as_float(v & 0xffff0000u); }
static __device__ __forceinline__ float bf1(unsigned short v) { return __uint_as_float(((unsigned)v) << 16); }
static __device__ __forceinline__ unsigned short f2bf(float f) {
  unsigned u = __float_as_uint(f);
  u += 0x7fffu + ((u >> 16) & 1u);
  return (unsigned short)(u >> 16);
}

// ---------------------------------------------------------------------------
// bf16 MFMA GEMM: C[M,Nout] = A[M,256] @ W[256,Nout], W pre-transposed bf16.
// ---------------------------------------------------------------------------
template <int BN, bool AF32, bool BIAS, bool RELU, bool OUTBF>
__global__ __launch_bounds__(256) void gemm_mfma(
    const void* __restrict__ Av, const unsigned short* __restrict__ Bt,
    const float* __restrict__ bias, void* __restrict__ Cv, int M, int Nout) {
  constexpr int LDA = 72;
  __shared__ __align__(16) unsigned short Al[128 * LDA];
  __shared__ __align__(16) unsigned short Bl[BN * LDA];
  const int t = threadIdx.x;
  const int w = t >> 6, lane = t & 63;
  const int quad = lane >> 4, l15 = lane & 15;
  const int row0 = blockIdx.x * 128;
  const int c0 = blockIdx.y * BN;
  constexpr int WR = (BN == 128) ? 4 : 2;
  const int wrow0 = (BN == 128) ? (w >> 1) * 64 : w * 32;
  const int wcol0 = (BN == 128) ? (w & 1) * 64 : 0;

  f32x4 acc[WR][4];
#pragma unroll
  for (int i = 0; i < WR; ++i)
#pragma unroll
    for (int j = 0; j < 4; ++j) acc[i][j] = (f32x4){0.f, 0.f, 0.f, 0.f};

  for (int k0 = 0; k0 < 256; k0 += 64) {
#pragma unroll
    for (int ci = 0; ci < 4; ++ci) {
      int id = ci * 256 + t;
      int r = id >> 3, cq = id & 7;
      int gr = row0 + r;
      uint4 pack = make_uint4(0, 0, 0, 0);
      if (AF32) {
        if (gr < M) {
          const float* ap = (const float*)Av + (size_t)gr * 256 + k0 + cq * 8;
          float4 f0 = *(const float4*)ap;
          float4 f1 = *(const float4*)(ap + 4);
          pack.x = (unsigned)f2bf(f0.x) | ((unsigned)f2bf(f0.y) << 16);
          pack.y = (unsigned)f2bf(f0.z) | ((unsigned)f2bf(f0.w) << 16);
          pack.z = (unsigned)f2bf(f1.x) | ((unsigned)f2bf(f1.y) << 16);
          pack.w = (unsigned)f2bf(f1.z) | ((unsigned)f2bf(f1.w) << 16);
        }
      } else {
        if (gr < M)
          pack = *(const uint4*)((const unsigned short*)Av + (size_t)gr * 256 + k0 + cq * 8);
      }
      *(uint4*)&Al[r * LDA + cq * 8] = pack;
    }
#pragma unroll
    for (int ci = 0; ci < BN / 32; ++ci) {
      int id = ci * 256 + t;
      int r = id >> 3, cq = id & 7;
      *(uint4*)&Bl[r * LDA + cq * 8] =
          *(const uint4*)(Bt + (size_t)(c0 + r) * 256 + k0 + cq * 8);
    }
    __syncthreads();
#pragma unroll
    for (int ks = 0; ks < 64; ks += 32) {
      bf16x8 af[WR], bfr[4];
#pragma unroll
      for (int i = 0; i < WR; ++i)
        af[i] = *(const bf16x8*)&Al[(wrow0 + i * 16 + l15) * LDA + ks + quad * 8];
#pragma unroll
      for (int j = 0; j < 4; ++j)
        bfr[j] = *(const bf16x8*)&Bl[(wcol0 + j * 16 + l15) * LDA + ks + quad * 8];
#pragma unroll
      for (int i = 0; i < WR; ++i)
#pragma unroll
        for (int j = 0; j < 4; ++j)
          acc[i][j] = __builtin_amdgcn_mfma_f32_16x16x32_bf16(af[i], bfr[j], acc[i][j], 0, 0, 0);
    }
    __syncthreads();
  }
#pragma unroll
  for (int i = 0; i < WR; ++i) {
#pragma unroll
    for (int j = 0; j < 4; ++j) {
      int col = c0 + wcol0 + j * 16 + l15;
      float bv = BIAS ? bias[col] : 0.f;
#pragma unroll
      for (int r = 0; r < 4; ++r) {
        int row = row0 + wrow0 + i * 16 + quad * 4 + r;
        if (row < M) {
          float v = acc[i][j][r] + bv;
          if (RELU) v = fmaxf(v, 0.f);
          if (OUTBF)
            ((unsigned short*)Cv)[(size_t)row * Nout + col] = f2bf(v);
          else
            ((float*)Cv)[(size_t)row * Nout + col] = v;
        }
      }
    }
  }
}

__global__ void trcvt_kernel(const float* __restrict__ in, unsigned short* __restrict__ out,
                             int Nout) {
  int id = blockIdx.x * blockDim.x + threadIdx.x;
  if (id < Nout * 256) {
    int k = id & 255, n = id >> 8;
    out[id] = f2bf(in[k * Nout + n]);
  }
}

// ---------------------------------------------------------------------------
// attention logits
// ---------------------------------------------------------------------------
__global__ __launch_bounds__(256) void al1_kernel(
    const unsigned short* __restrict__ xp, const float* __restrict__ asrc,
    const float* __restrict__ adst, float* __restrict__ als, float* __restrict__ ald, int nn) {
  int wid = (blockIdx.x * blockDim.x + threadIdx.x) >> 6;
  int lane = threadIdx.x & 63;
  if (wid >= nn) return;
  uint2 v = *(const uint2*)(xp + (size_t)wid * 256 + lane * 4);
  float4 as4 = *(const float4*)(asrc + lane * 4);
  float4 ad4 = *(const float4*)(adst + lane * 4);
  float x0 = bflo(v.x), x1 = bfhi(v.x), x2 = bflo(v.y), x3 = bfhi(v.y);
  float ps = x0 * as4.x + x1 * as4.y + x2 * as4.z + x3 * as4.w;
  float pd = x0 * ad4.x + x1 * ad4.y + x2 * ad4.z + x3 * ad4.w;
#pragma unroll
  for (int o = 8; o; o >>= 1) {
    ps += __shfl_xor(ps, o, 64);
    pd += __shfl_xor(pd, o, 64);
  }
  if ((lane & 15) == 0) {
    als[wid * 4 + (lane >> 4)] = ps;
    ald[wid * 4 + (lane >> 4)] = pd;
  }
}

__global__ __launch_bounds__(256) void al2_kernel(
    const unsigned short* __restrict__ xp2, const float* __restrict__ asrc,
    const float* __restrict__ adst, float* __restrict__ als, float* __restrict__ ald, int nn) {
  int wid = (blockIdx.x * blockDim.x + threadIdx.x) >> 6;
  int lane = threadIdx.x & 63;
  if (wid >= nn) return;
  float x = bf1(xp2[(size_t)wid * 64 + lane]);
  float ps = x * asrc[lane];
  float pd = x * adst[lane];
#pragma unroll
  for (int o = 32; o; o >>= 1) {
    ps += __shfl_xor(ps, o, 64);
    pd += __shfl_xor(pd, o, 64);
  }
  if (lane == 0) {
    als[wid] = ps;
    ald[wid] = pd;
  }
}

// ---------------------------------------------------------------------------
// CSR build — hierarchical scan
// ---------------------------------------------------------------------------
__global__ void count_kernel(const int* __restrict__ dst, int E, int* __restrict__ cnt) {
  int e = blockIdx.x * blockDim.x + threadIdx.x;
  if (e < E) atomicAdd(&cnt[dst[e]], 1);
}

__global__ __launch_bounds__(256) void scan_blocks(
    const int* __restrict__ cnt, int n, int* __restrict__ offs, int* __restrict__ bsum) {
  int t = threadIdx.x;
  int base = blockIdx.x * 1024 + t * 4;
  int4 v = make_int4(0, 0, 0, 0);
  if (base + 3 < n) {
    v = *(const int4*)(cnt + base);
  } else {
    if (base + 0 < n) v.x = cnt[base + 0];
    if (base + 1 < n) v.y = cnt[base + 1];
    if (base + 2 < n) v.z = cnt[base + 2];
  }
  int s = v.x + v.y + v.z + v.w;
  int lane = t & 63, w = t >> 6;
  int sc = s;
#pragma unroll
  for (int o = 1; o < 64; o <<= 1) {
    int u = __shfl_up(sc, o, 64);
    if (lane >= o) sc += u;
  }
  __shared__ int wsum[4];
  if (lane == 63) wsum[w] = sc;
  __syncthreads();
  int woff = 0;
#pragma unroll
  for (int i = 0; i < 4; ++i)
    if (i < w) woff += wsum[i];
  int excl = woff + sc - s;
  int o0 = excl, o1 = o0 + v.x, o2 = o1 + v.y, o3 = o2 + v.z;
  if (base + 3 < n) {
    *(int4*)(offs + base) = make_int4(o0, o1, o2, o3);
  } else {
    if (base + 0 < n) offs[base + 0] = o0;
    if (base + 1 < n) offs[base + 1] = o1;
    if (base + 2 < n) offs[base + 2] = o2;
  }
  if (t == 255) bsum[blockIdx.x] = woff + sc;
}

__global__ void scan_top(const int* __restrict__ bsum, int nb, int* __restrict__ boff,
                         int* __restrict__ offs, int n) {
  int lane = threadIdx.x;
  int s = (lane < nb) ? bsum[lane] : 0;
  int sc = s;
#pragma unroll
  for (int o = 1; o < 64; o <<= 1) {
    int u = __shfl_up(sc, o, 64);
    if (lane >= o) sc += u;
  }
  if (lane < nb) boff[lane] = sc - s;
  if (lane == 63) offs[n] = sc;
}

__global__ __launch_bounds__(256) void scan_add(
    int* __restrict__ offs, int* __restrict__ cur, const int* __restrict__ boff, int n) {
  int t = threadIdx.x;
  int base = blockIdx.x * 1024 + t * 4;
  int b = boff[blockIdx.x];
  if (base + 3 < n) {
    int4 v = *(const int4*)(offs + base);
    v.x += b; v.y += b; v.z += b; v.w += b;
    *(int4*)(offs + base) = v;
    *(int4*)(cur + base) = v;
  } else {
    for (int i = 0; i < 4; ++i)
      if (base + i < n) {
        int v = offs[base + i] + b;
        offs[base + i] = v;
        cur[base + i] = v;
      }
  }
}

__global__ void fill_kernel(const int* __restrict__ dst, const int* __restrict__ src, int E,
                            int* __restrict__ cur, int* __restrict__ csrc) {
  int e = blockIdx.x * blockDim.x + threadIdx.x;
  if (e < E) {
    int p = atomicAdd(&cur[dst[e]], 1);
    csrc[p] = src[e];
  }
}

// ---------------------------------------------------------------------------
// agg1 v2: wave per dst node. Phase 1: lane-parallel max; Phase 2:
// lane-parallel denom; Phase 3: channel-parallel weighted sum (no serial
// chain -> unroll x2, 2 in-flight gathers).
// ---------------------------------------------------------------------------
__global__ __launch_bounds__(256) void agg1_kernel(
    const unsigned short* __restrict__ xp, const float* __restrict__ als,
    const float* __restrict__ ald, const int* __restrict__ offs,
    const int* __restrict__ csrc, const float* __restrict__ b1,
    unsigned short* __restrict__ hout, int nn) {
  int n = (blockIdx.x * blockDim.x + threadIdx.x) >> 6;
  int lane = threadIdx.x & 63;
  if (n >= nn) return;
  float4 aldn = *(const float4*)(ald + (size_t)n * 4);
  float4 alsn = *(const float4*)(als + (size_t)n * 4);
  float s0 = lrelu(alsn.x + aldn.x), s1 = lrelu(alsn.y + aldn.y);
  float s2 = lrelu(alsn.z + aldn.z), s3 = lrelu(alsn.w + aldn.w);
  int i0 = offs[n], i1 = offs[n + 1];

  // phase 1: per-head max (self-loop as init)
  float m0 = s0, m1 = s1, m2 = s2, m3 = s3;
  for (int i = i0 + lane; i < i1; i += 64) {
    int s = csrc[i];
    float4 a4 = *(const float4*)(als + (size_t)s * 4);
    m0 = fmaxf(m0, lrelu(a4.x + aldn.x));
    m1 = fmaxf(m1, lrelu(a4.y + aldn.y));
    m2 = fmaxf(m2, lrelu(a4.z + aldn.z));
    m3 = fmaxf(m3, lrelu(a4.w + aldn.w));
  }
#pragma unroll
  for (int o = 32; o; o >>= 1) {
    m0 = fmaxf(m0, __shfl_xor(m0, o, 64));
    m1 = fmaxf(m1, __shfl_xor(m1, o, 64));
    m2 = fmaxf(m2, __shfl_xor(m2, o, 64));
    m3 = fmaxf(m3, __shfl_xor(m3, o, 64));
  }
  // phase 2: denom
  float d0 = 0.f, d1 = 0.f, d2 = 0.f, d3 = 0.f;
  for (int i = i0 + lane; i < i1; i += 64) {
    int s = csrc[i];
    float4 a4 = *(const float4*)(als + (size_t)s * 4);
    d0 += __expf(lrelu(a4.x + aldn.x) - m0);
    d1 += __expf(lrelu(a4.y + aldn.y) - m1);
    d2 += __expf(lrelu(a4.z + aldn.z) - m2);
    d3 += __expf(lrelu(a4.w + aldn.w) - m3);
  }
#pragma unroll
  for (int o = 32; o; o >>= 1) {
    d0 += __shfl_xor(d0, o, 64);
    d1 += __shfl_xor(d1, o, 64);
    d2 += __shfl_xor(d2, o, 64);
    d3 += __shfl_xor(d3, o, 64);
  }
  float w0 = __expf(s0 - m0), w1 = __expf(s1 - m1);
  float w2 = __expf(s2 - m2), w3 = __expf(s3 - m3);
  d0 += w0; d1 += w1; d2 += w2; d3 += w3;

  // phase 3: channel-parallel weighted sum
  int h = lane >> 4;
  float mh = (h == 0) ? m0 : (h == 1) ? m1 : (h == 2) ? m2 : m3;
  float adh = (h == 0) ? aldn.x : (h == 1) ? aldn.y : (h == 2) ? aldn.z : aldn.w;
  float selfw = (h == 0) ? w0 : (h == 1) ? w1 : (h == 2) ? w2 : w3;
  float invh = 1.f / ((h == 0) ? d0 : (h == 1) ? d1 : (h == 2) ? d2 : d3);

  uint2 v = *(const uint2*)(xp + (size_t)n * 256 + lane * 4);
  float a0 = selfw * bflo(v.x), a1 = selfw * bfhi(v.x);
  float a2 = selfw * bflo(v.y), a3 = selfw * bfhi(v.y);

  int i = i0;
  for (; i + 1 < i1; i += 2) {
    int sa = csrc[i], sb = csrc[i + 1];
    uint2 ua = *(const uint2*)(xp + (size_t)sa * 256 + lane * 4);
    uint2 ub = *(const uint2*)(xp + (size_t)sb * 256 + lane * 4);
    float wa = __expf(lrelu(als[(size_t)sa * 4 + h] + adh) - mh);
    float wb = __expf(lrelu(als[(size_t)sb * 4 + h] + adh) - mh);
    a0 += wa * bflo(ua.x); a1 += wa * bfhi(ua.x);
    a2 += wa * bflo(ua.y); a3 += wa * bfhi(ua.y);
    a0 += wb * bflo(ub.x); a1 += wb * bfhi(ub.x);
    a2 += wb * bflo(ub.y); a3 += wb * bfhi(ub.y);
  }
  if (i < i1) {
    int sa = csrc[i];
    uint2 ua = *(const uint2*)(xp + (size_t)sa * 256 + lane * 4);
    float wa = __expf(lrelu(als[(size_t)sa * 4 + h] + adh) - mh);
    a0 += wa * bflo(ua.x); a1 += wa * bfhi(ua.x);
    a2 += wa * bflo(ua.y); a3 += wa * bfhi(ua.y);
  }
  float4 bb = *(const float4*)(b1 + lane * 4);
  float o0 = a0 * invh + bb.x, o1 = a1 * invh + bb.y;
  float o2 = a2 * invh + bb.z, o3 = a3 * invh + bb.w;
  o0 = o0 > 0.f ? o0 : __expf(o0) - 1.f;
  o1 = o1 > 0.f ? o1 : __expf(o1) - 1.f;
  o2 = o2 > 0.f ? o2 : __expf(o2) - 1.f;
  o3 = o3 > 0.f ? o3 : __expf(o3) - 1.f;
  uint2 p;
  p.x = (unsigned)f2bf(o0) | ((unsigned)f2bf(o1) << 16);
  p.y = (unsigned)f2bf(o2) | ((unsigned)f2bf(o3) << 16);
  *(uint2*)(hout + (size_t)n * 256 + lane * 4) = p;
}

// agg2 v2: same 3-phase structure, 1 head, fuse +b2 +skip.
__global__ __launch_bounds__(256) void agg2_kernel(
    const unsigned short* __restrict__ xp2, const float* __restrict__ als,
    const float* __restrict__ ald, const int* __restrict__ offs,
    const int* __restrict__ csrc, const float* __restrict__ b2,
    const float* __restrict__ skip, float* __restrict__ out, int nn) {
  int n = (blockIdx.x * blockDim.x + threadIdx.x) >> 6;
  int lane = threadIdx.x & 63;
  if (n >= nn) return;
  float aldn = ald[n];
  float sl = lrelu(als[n] + aldn);
  int i0 = offs[n], i1 = offs[n + 1];

  float m = sl;
  for (int i = i0 + lane; i < i1; i += 64)
    m = fmaxf(m, lrelu(als[csrc[i]] + aldn));
#pragma unroll
  for (int o = 32; o; o >>= 1) m = fmaxf(m, __shfl_xor(m, o, 64));

  float d = 0.f;
  for (int i = i0 + lane; i < i1; i += 64)
    d += __expf(lrelu(als[csrc[i]] + aldn) - m);
#pragma unroll
  for (int o = 32; o; o >>= 1) d += __shfl_xor(d, o, 64);
  float selfw = __expf(sl - m);
  d += selfw;
  float inv = 1.f / d;

  float acc = selfw * bf1(xp2[(size_t)n * 64 + lane]);
  int i = i0;
  for (; i + 1 < i1; i += 2) {
    int sa = csrc[i], sb = csrc[i + 1];
    float xa = bf1(xp2[(size_t)sa * 64 + lane]);
    float xb = bf1(xp2[(size_t)sb * 64 + lane]);
    float wa = __expf(lrelu(als[sa] + aldn) - m);
    float wb = __expf(lrelu(als[sb] + aldn) - m);
    acc += wa * xa + wb * xb;
  }
  if (i < i1) {
    int sa = csrc[i];
    acc += __expf(lrelu(als[sa] + aldn) - m) * bf1(xp2[(size_t)sa * 64 + lane]);
  }
  out[(size_t)n * 64 + lane] = acc * inv + b2[lane] + skip[(size_t)n * 64 + lane];
}

// ---------------------------------------------------------------------------
extern "C" void kernel_launch(void* const* d_in, const int* in_sizes, int n_in,
                              void* d_out, int out_size, void* d_ws, size_t ws_size,
                              hipStream_t stream) {
  const float* x_clean = (const float*)d_in[0];
  const float* x_noised = (const float*)d_in[1];
  const int* esrc = (const int*)d_in[2];
  const int* edst = (const int*)d_in[3];
  const float* W1 = (const float*)d_in[4];
  const float* a_src1 = (const float*)d_in[5];
  const float* a_dst1 = (const float*)d_in[6];
  const float* b1 = (const float*)d_in[7];
  const float* W2 = (const float*)d_in[8];
  const float* a_src2 = (const float*)d_in[9];
  const float* a_dst2 = (const float*)d_in[10];
  const float* b2 = (const float*)d_in[11];
  float* out = (float*)d_out;

  const int N = in_sizes[0] / 256;  // 50000
  const int E = in_sizes[2];        // 800000

  unsigned short* W1t = (unsigned short*)d_ws;      // 256*256
  unsigned short* W2t = W1t + 65536;                // 64*256
  unsigned short* xp1 = W2t + 16384;                // N*256 bf16
  unsigned short* hs = xp1 + (size_t)N * 256;       // N*256 bf16 (hs, then h)
  unsigned short* xp2 = hs + (size_t)N * 256;       // N*64 bf16
  float* skip = (float*)(xp2 + (size_t)N * 64);     // N*64 f32
  float* als1 = skip + (size_t)N * 64;              // N*4
  float* ald1 = als1 + (size_t)N * 4;               // N*4
  float* als2 = ald1 + (size_t)N * 4;               // N
  float* ald2 = als2 + N;                           // N
  int* cnt = (int*)(ald2 + N);                      // N
  int* offs = cnt + N;                              // N+1
  int* cur = offs + N + 1;                          // N
  int* csrc = cur + N;                              // E
  int* bsum = csrc + E;                             // <=64
  int* boff = bsum + 64;                            // <=64

  const int gemm_rows = (N + 127) / 128;  // 391
  dim3 block256(256);
  const int wave_grid = (N * 64 + 255) / 256;  // 12500
  const int edge_grid = (E + 255) / 256;
  const int nb = (N + 1023) / 1024;

  hipLaunchKernelGGL(trcvt_kernel, dim3(256), block256, 0, stream, W1, W1t, 256);
  hipLaunchKernelGGL(trcvt_kernel, dim3(64), block256, 0, stream, W2, W2t, 64);
  hipLaunchKernelGGL((gemm_mfma<128, true, false, false, true>), dim3(gemm_rows, 2), block256,
                     0, stream, x_noised, W1t, nullptr, xp1, N, 256);
  hipLaunchKernelGGL((gemm_mfma<128, true, true, true, true>), dim3(gemm_rows, 2), block256,
                     0, stream, x_clean, W1t, b1, hs, N, 256);
  hipLaunchKernelGGL((gemm_mfma<64, false, true, false, false>), dim3(gemm_rows, 1), block256,
                     0, stream, hs, W2t, b2, skip, N, 64);
  hipLaunchKernelGGL(al1_kernel, dim3(wave_grid), block256, 0, stream,
                     xp1, a_src1, a_dst1, als1, ald1, N);
  hipMemsetAsync(cnt, 0, (size_t)N * sizeof(int), stream);
  hipLaunchKernelGGL(count_kernel, dim3(edge_grid), block256, 0, stream, edst, E, cnt);
  hipLaunchKernelGGL(scan_blocks, dim3(nb), block256, 0, stream, cnt, N, offs, bsum);
  hipLaunchKernelGGL(scan_top, dim3(1), dim3(64), 0, stream, bsum, nb, boff, offs, N);
  hipLaunchKernelGGL(scan_add, dim3(nb), block256, 0, stream, offs, cur, boff, N);
  hipLaunchKernelGGL(fill_kernel, dim3(edge_grid), block256, 0, stream, edst, esrc, E, cur, csrc);
  hipLaunchKernelGGL(agg1_kernel, dim3(wave_grid), block256, 0, stream,
                     xp1, als1, ald1, offs, csrc, b1, hs, N);
  hipLaunchKernelGGL((gemm_mfma<64, false, false, false, true>), dim3(gemm_rows, 1), block256,
                     0, stream, hs, W2t, nullptr, xp2, N, 64);
  hipLaunchKernelGGL(al2_kernel, dim3(wave_grid), block256, 0, stream,
                     xp2, a_src2, a_dst2, als2, ald2, N);
  hipLaunchKernelGGL(agg2_kernel, dim3(wave_grid), block256, 0, stream,
                     xp2, als2, ald2, offs, csrc, b2, skip, out, N);
}

// Round 5
// 445.990 us; speedup vs baseline: 2.1862x; 1.0829x over previous
//
#include <hip/hip_runtime.h>
#include <hip/hip_bf16.h>
#include <cstdint>

typedef __bf16 bf16x8 __attribute__((ext_vector_type(8)));
typedef float f32x4 __attribute__((ext_vector_type(4)));

static __device__ __forceinline__ float lrelu(float x) { return x > 0.f ? x : 0.2f * x; }
static __device__ __forceinline__ float bflo(unsigned v) { return __uint_as_float(v << 16); }
static __device__ __forceinline__ float bfhi(unsigned v) { return __uint_as_float(v & 0xffff0000u); }
static __device__ __forceinline__ float bf1(unsigned short v) { return __uint_as_float(((unsigned)v) << 16); }
static __device__ __forceinline__ unsigned short f2bf(float f) {
  unsigned u = __float_as_uint(f);
  u += 0x7fffu + ((u >> 16) & 1u);
  return (unsigned short)(u >> 16);
}

// ---------------------------------------------------------------------------
// bf16 MFMA GEMM: C[M,Nout] = A[M,256] @ W[256,Nout], W pre-transposed bf16.
// ---------------------------------------------------------------------------
template <int BN, bool AF32, bool BIAS, bool RELU, bool OUTBF>
__global__ __launch_bounds__(256) void gemm_mfma(
    const void* __restrict__ Av, const unsigned short* __restrict__ Bt,
    const float* __restrict__ bias, void* __restrict__ Cv, int M, int Nout) {
  constexpr int LDA = 72;
  __shared__ __align__(16) unsigned short Al[128 * LDA];
  __shared__ __align__(16) unsigned short Bl[BN * LDA];
  const int t = threadIdx.x;
  const int w = t >> 6, lane = t & 63;
  const int quad = lane >> 4, l15 = lane & 15;
  const int row0 = blockIdx.x * 128;
  const int c0 = blockIdx.y * BN;
  constexpr int WR = (BN == 128) ? 4 : 2;
  const int wrow0 = (BN == 128) ? (w >> 1) * 64 : w * 32;
  const int wcol0 = (BN == 128) ? (w & 1) * 64 : 0;

  f32x4 acc[WR][4];
#pragma unroll
  for (int i = 0; i < WR; ++i)
#pragma unroll
    for (int j = 0; j < 4; ++j) acc[i][j] = (f32x4){0.f, 0.f, 0.f, 0.f};

  for (int k0 = 0; k0 < 256; k0 += 64) {
#pragma unroll
    for (int ci = 0; ci < 4; ++ci) {
      int id = ci * 256 + t;
      int r = id >> 3, cq = id & 7;
      int gr = row0 + r;
      uint4 pack = make_uint4(0, 0, 0, 0);
      if (AF32) {
        if (gr < M) {
          const float* ap = (const float*)Av + (size_t)gr * 256 + k0 + cq * 8;
          float4 f0 = *(const float4*)ap;
          float4 f1 = *(const float4*)(ap + 4);
          pack.x = (unsigned)f2bf(f0.x) | ((unsigned)f2bf(f0.y) << 16);
          pack.y = (unsigned)f2bf(f0.z) | ((unsigned)f2bf(f0.w) << 16);
          pack.z = (unsigned)f2bf(f1.x) | ((unsigned)f2bf(f1.y) << 16);
          pack.w = (unsigned)f2bf(f1.z) | ((unsigned)f2bf(f1.w) << 16);
        }
      } else {
        if (gr < M)
          pack = *(const uint4*)((const unsigned short*)Av + (size_t)gr * 256 + k0 + cq * 8);
      }
      *(uint4*)&Al[r * LDA + cq * 8] = pack;
    }
#pragma unroll
    for (int ci = 0; ci < BN / 32; ++ci) {
      int id = ci * 256 + t;
      int r = id >> 3, cq = id & 7;
      *(uint4*)&Bl[r * LDA + cq * 8] =
          *(const uint4*)(Bt + (size_t)(c0 + r) * 256 + k0 + cq * 8);
    }
    __syncthreads();
#pragma unroll
    for (int ks = 0; ks < 64; ks += 32) {
      bf16x8 af[WR], bfr[4];
#pragma unroll
      for (int i = 0; i < WR; ++i)
        af[i] = *(const bf16x8*)&Al[(wrow0 + i * 16 + l15) * LDA + ks + quad * 8];
#pragma unroll
      for (int j = 0; j < 4; ++j)
        bfr[j] = *(const bf16x8*)&Bl[(wcol0 + j * 16 + l15) * LDA + ks + quad * 8];
#pragma unroll
      for (int i = 0; i < WR; ++i)
#pragma unroll
        for (int j = 0; j < 4; ++j)
          acc[i][j] = __builtin_amdgcn_mfma_f32_16x16x32_bf16(af[i], bfr[j], acc[i][j], 0, 0, 0);
    }
    __syncthreads();
  }
#pragma unroll
  for (int i = 0; i < WR; ++i) {
#pragma unroll
    for (int j = 0; j < 4; ++j) {
      int col = c0 + wcol0 + j * 16 + l15;
      float bv = BIAS ? bias[col] : 0.f;
#pragma unroll
      for (int r = 0; r < 4; ++r) {
        int row = row0 + wrow0 + i * 16 + quad * 4 + r;
        if (row < M) {
          float v = acc[i][j][r] + bv;
          if (RELU) v = fmaxf(v, 0.f);
          if (OUTBF)
            ((unsigned short*)Cv)[(size_t)row * Nout + col] = f2bf(v);
          else
            ((float*)Cv)[(size_t)row * Nout + col] = v;
        }
      }
    }
  }
}

__global__ void trcvt_kernel(const float* __restrict__ in, unsigned short* __restrict__ out,
                             int Nout) {
  int id = blockIdx.x * blockDim.x + threadIdx.x;
  if (id < Nout * 256) {
    int k = id & 255, n = id >> 8;
    out[id] = f2bf(in[k * Nout + n]);
  }
}

// ---------------------------------------------------------------------------
// attention logits
// ---------------------------------------------------------------------------
__global__ __launch_bounds__(256) void al1_kernel(
    const unsigned short* __restrict__ xp, const float* __restrict__ asrc,
    const float* __restrict__ adst, float* __restrict__ als, float* __restrict__ ald, int nn) {
  int wid = (blockIdx.x * blockDim.x + threadIdx.x) >> 6;
  int lane = threadIdx.x & 63;
  if (wid >= nn) return;
  uint2 v = *(const uint2*)(xp + (size_t)wid * 256 + lane * 4);
  float4 as4 = *(const float4*)(asrc + lane * 4);
  float4 ad4 = *(const float4*)(adst + lane * 4);
  float x0 = bflo(v.x), x1 = bfhi(v.x), x2 = bflo(v.y), x3 = bfhi(v.y);
  float ps = x0 * as4.x + x1 * as4.y + x2 * as4.z + x3 * as4.w;
  float pd = x0 * ad4.x + x1 * ad4.y + x2 * ad4.z + x3 * ad4.w;
#pragma unroll
  for (int o = 8; o; o >>= 1) {
    ps += __shfl_xor(ps, o, 64);
    pd += __shfl_xor(pd, o, 64);
  }
  if ((lane & 15) == 0) {
    als[wid * 4 + (lane >> 4)] = ps;
    ald[wid * 4 + (lane >> 4)] = pd;
  }
}

__global__ __launch_bounds__(256) void al2_kernel(
    const unsigned short* __restrict__ xp2, const float* __restrict__ asrc,
    const float* __restrict__ adst, float* __restrict__ als, float* __restrict__ ald, int nn) {
  int wid = (blockIdx.x * blockDim.x + threadIdx.x) >> 6;
  int lane = threadIdx.x & 63;
  if (wid >= nn) return;
  float x = bf1(xp2[(size_t)wid * 64 + lane]);
  float ps = x * asrc[lane];
  float pd = x * adst[lane];
#pragma unroll
  for (int o = 32; o; o >>= 1) {
    ps += __shfl_xor(ps, o, 64);
    pd += __shfl_xor(pd, o, 64);
  }
  if (lane == 0) {
    als[wid] = ps;
    ald[wid] = pd;
  }
}

// ---------------------------------------------------------------------------
// CSR build — hierarchical scan
// ---------------------------------------------------------------------------
__global__ void count_kernel(const int* __restrict__ dst, int E, int* __restrict__ cnt) {
  int e = blockIdx.x * blockDim.x + threadIdx.x;
  if (e < E) atomicAdd(&cnt[dst[e]], 1);
}

__global__ __launch_bounds__(256) void scan_blocks(
    const int* __restrict__ cnt, int n, int* __restrict__ offs, int* __restrict__ bsum) {
  int t = threadIdx.x;
  int base = blockIdx.x * 1024 + t * 4;
  int4 v = make_int4(0, 0, 0, 0);
  if (base + 3 < n) {
    v = *(const int4*)(cnt + base);
  } else {
    if (base + 0 < n) v.x = cnt[base + 0];
    if (base + 1 < n) v.y = cnt[base + 1];
    if (base + 2 < n) v.z = cnt[base + 2];
  }
  int s = v.x + v.y + v.z + v.w;
  int lane = t & 63, w = t >> 6;
  int sc = s;
#pragma unroll
  for (int o = 1; o < 64; o <<= 1) {
    int u = __shfl_up(sc, o, 64);
    if (lane >= o) sc += u;
  }
  __shared__ int wsum[4];
  if (lane == 63) wsum[w] = sc;
  __syncthreads();
  int woff = 0;
#pragma unroll
  for (int i = 0; i < 4; ++i)
    if (i < w) woff += wsum[i];
  int excl = woff + sc - s;
  int o0 = excl, o1 = o0 + v.x, o2 = o1 + v.y, o3 = o2 + v.z;
  if (base + 3 < n) {
    *(int4*)(offs + base) = make_int4(o0, o1, o2, o3);
  } else {
    if (base + 0 < n) offs[base + 0] = o0;
    if (base + 1 < n) offs[base + 1] = o1;
    if (base + 2 < n) offs[base + 2] = o2;
  }
  if (t == 255) bsum[blockIdx.x] = woff + sc;
}

__global__ void scan_top(const int* __restrict__ bsum, int nb, int* __restrict__ boff,
                         int* __restrict__ offs, int n) {
  int lane = threadIdx.x;
  int s = (lane < nb) ? bsum[lane] : 0;
  int sc = s;
#pragma unroll
  for (int o = 1; o < 64; o <<= 1) {
    int u = __shfl_up(sc, o, 64);
    if (lane >= o) sc += u;
  }
  if (lane < nb) boff[lane] = sc - s;
  if (lane == 63) offs[n] = sc;
}

__global__ __launch_bounds__(256) void scan_add(
    int* __restrict__ offs, int* __restrict__ cur, const int* __restrict__ boff, int n) {
  int t = threadIdx.x;
  int base = blockIdx.x * 1024 + t * 4;
  int b = boff[blockIdx.x];
  if (base + 3 < n) {
    int4 v = *(const int4*)(offs + base);
    v.x += b; v.y += b; v.z += b; v.w += b;
    *(int4*)(offs + base) = v;
    *(int4*)(cur + base) = v;
  } else {
    for (int i = 0; i < 4; ++i)
      if (base + i < n) {
        int v = offs[base + i] + b;
        offs[base + i] = v;
        cur[base + i] = v;
      }
  }
}

__global__ void fill_kernel(const int* __restrict__ dst, const int* __restrict__ src, int E,
                            int* __restrict__ cur, int* __restrict__ csrc) {
  int e = blockIdx.x * blockDim.x + threadIdx.x;
  if (e < E) {
    int p = atomicAdd(&cur[dst[e]], 1);
    csrc[p] = src[e];
  }
}

// ---------------------------------------------------------------------------
// agg1 v3: wave per dst node. No max subtraction (logits bounded ~|13|,
// exp safe in fp32). Pass A: lane-parallel denom + stash per-edge weights
// in LDS (CAP edges). Pass B: channel-parallel weighted sum reading
// wave-scalar weights from LDS (broadcast), unroll x4. Tail edges beyond
// CAP recompute inline (never in practice; correctness only).
// ---------------------------------------------------------------------------
#define CAP1 80
__global__ __launch_bounds__(256) void agg1_kernel(
    const unsigned short* __restrict__ xp, const float* __restrict__ als,
    const float* __restrict__ ald, const int* __restrict__ offs,
    const int* __restrict__ csrc, const float* __restrict__ b1,
    unsigned short* __restrict__ hout, int nn) {
  __shared__ float ews[4][CAP1 * 4];
  int wv = threadIdx.x >> 6;
  int n = (blockIdx.x * blockDim.x + threadIdx.x) >> 6;
  int lane = threadIdx.x & 63;
  if (n >= nn) return;
  float4 aldn = *(const float4*)(ald + (size_t)n * 4);
  float4 alsn = *(const float4*)(als + (size_t)n * 4);
  float w0 = __expf(lrelu(alsn.x + aldn.x)), w1 = __expf(lrelu(alsn.y + aldn.y));
  float w2 = __expf(lrelu(alsn.z + aldn.z)), w3 = __expf(lrelu(alsn.w + aldn.w));
  int i0 = offs[n], i1 = offs[n + 1];

  // pass A: denom + weight stash
  float d0 = 0.f, d1 = 0.f, d2 = 0.f, d3 = 0.f;
  for (int i = i0 + lane; i < i1; i += 64) {
    int s = csrc[i];
    float4 a4 = *(const float4*)(als + (size_t)s * 4);
    float e0 = __expf(lrelu(a4.x + aldn.x));
    float e1 = __expf(lrelu(a4.y + aldn.y));
    float e2 = __expf(lrelu(a4.z + aldn.z));
    float e3 = __expf(lrelu(a4.w + aldn.w));
    d0 += e0; d1 += e1; d2 += e2; d3 += e3;
    int j = i - i0;
    if (j < CAP1) *(float4*)&ews[wv][j * 4] = make_float4(e0, e1, e2, e3);
  }
#pragma unroll
  for (int o = 32; o; o >>= 1) {
    d0 += __shfl_xor(d0, o, 64);
    d1 += __shfl_xor(d1, o, 64);
    d2 += __shfl_xor(d2, o, 64);
    d3 += __shfl_xor(d3, o, 64);
  }
  d0 += w0; d1 += w1; d2 += w2; d3 += w3;

  // pass B: channel-parallel weighted sum
  int h = lane >> 4;
  float selfw = (h == 0) ? w0 : (h == 1) ? w1 : (h == 2) ? w2 : w3;
  float invh = 1.f / ((h == 0) ? d0 : (h == 1) ? d1 : (h == 2) ? d2 : d3);
  float adh = (h == 0) ? aldn.x : (h == 1) ? aldn.y : (h == 2) ? aldn.z : aldn.w;

  uint2 v = *(const uint2*)(xp + (size_t)n * 256 + lane * 4);
  float a0 = selfw * bflo(v.x), a1 = selfw * bfhi(v.x);
  float a2 = selfw * bflo(v.y), a3 = selfw * bfhi(v.y);

  int lim = min(i1, i0 + CAP1);
  int i = i0;
  for (; i + 3 < lim; i += 4) {
    int j = i - i0;
    int sa = csrc[i], sb = csrc[i + 1], sc_ = csrc[i + 2], sd = csrc[i + 3];
    uint2 ua = *(const uint2*)(xp + (size_t)sa * 256 + lane * 4);
    uint2 ub = *(const uint2*)(xp + (size_t)sb * 256 + lane * 4);
    uint2 uc = *(const uint2*)(xp + (size_t)sc_ * 256 + lane * 4);
    uint2 ud = *(const uint2*)(xp + (size_t)sd * 256 + lane * 4);
    float wa = ews[wv][(j + 0) * 4 + h];
    float wb = ews[wv][(j + 1) * 4 + h];
    float wc = ews[wv][(j + 2) * 4 + h];
    float wd = ews[wv][(j + 3) * 4 + h];
    a0 += wa * bflo(ua.x) + wb * bflo(ub.x) + wc * bflo(uc.x) + wd * bflo(ud.x);
    a1 += wa * bfhi(ua.x) + wb * bfhi(ub.x) + wc * bfhi(uc.x) + wd * bfhi(ud.x);
    a2 += wa * bflo(ua.y) + wb * bflo(ub.y) + wc * bflo(uc.y) + wd * bflo(ud.y);
    a3 += wa * bfhi(ua.y) + wb * bfhi(ub.y) + wc * bfhi(uc.y) + wd * bfhi(ud.y);
  }
  for (; i < lim; ++i) {
    int j = i - i0;
    int sa = csrc[i];
    uint2 ua = *(const uint2*)(xp + (size_t)sa * 256 + lane * 4);
    float wa = ews[wv][j * 4 + h];
    a0 += wa * bflo(ua.x); a1 += wa * bfhi(ua.x);
    a2 += wa * bflo(ua.y); a3 += wa * bfhi(ua.y);
  }
  for (; i < i1; ++i) {  // cold tail: deg > CAP1
    int sa = csrc[i];
    uint2 ua = *(const uint2*)(xp + (size_t)sa * 256 + lane * 4);
    float wa = __expf(lrelu(als[(size_t)sa * 4 + h] + adh));
    a0 += wa * bflo(ua.x); a1 += wa * bfhi(ua.x);
    a2 += wa * bflo(ua.y); a3 += wa * bfhi(ua.y);
  }
  float4 bb = *(const float4*)(b1 + lane * 4);
  float o0 = a0 * invh + bb.x, o1 = a1 * invh + bb.y;
  float o2 = a2 * invh + bb.z, o3 = a3 * invh + bb.w;
  o0 = o0 > 0.f ? o0 : __expf(o0) - 1.f;
  o1 = o1 > 0.f ? o1 : __expf(o1) - 1.f;
  o2 = o2 > 0.f ? o2 : __expf(o2) - 1.f;
  o3 = o3 > 0.f ? o3 : __expf(o3) - 1.f;
  uint2 p;
  p.x = (unsigned)f2bf(o0) | ((unsigned)f2bf(o1) << 16);
  p.y = (unsigned)f2bf(o2) | ((unsigned)f2bf(o3) << 16);
  *(uint2*)(hout + (size_t)n * 256 + lane * 4) = p;
}

// agg2 v3: same structure, 1 head, fuse +b2 +skip.
#define CAP2 128
__global__ __launch_bounds__(256) void agg2_kernel(
    const unsigned short* __restrict__ xp2, const float* __restrict__ als,
    const float* __restrict__ ald, const int* __restrict__ offs,
    const int* __restrict__ csrc, const float* __restrict__ b2,
    const float* __restrict__ skip, float* __restrict__ out, int nn) {
  __shared__ float ews[4][CAP2];
  int wv = threadIdx.x >> 6;
  int n = (blockIdx.x * blockDim.x + threadIdx.x) >> 6;
  int lane = threadIdx.x & 63;
  if (n >= nn) return;
  float aldn = ald[n];
  float selfw = __expf(lrelu(als[n] + aldn));
  int i0 = offs[n], i1 = offs[n + 1];

  float d = 0.f;
  for (int i = i0 + lane; i < i1; i += 64) {
    float e = __expf(lrelu(als[csrc[i]] + aldn));
    d += e;
    int j = i - i0;
    if (j < CAP2) ews[wv][j] = e;
  }
#pragma unroll
  for (int o = 32; o; o >>= 1) d += __shfl_xor(d, o, 64);
  d += selfw;
  float inv = 1.f / d;

  float acc = selfw * bf1(xp2[(size_t)n * 64 + lane]);
  int lim = min(i1, i0 + CAP2);
  int i = i0;
  for (; i + 3 < lim; i += 4) {
    int j = i - i0;
    int sa = csrc[i], sb = csrc[i + 1], sc_ = csrc[i + 2], sd = csrc[i + 3];
    float xa = bf1(xp2[(size_t)sa * 64 + lane]);
    float xb = bf1(xp2[(size_t)sb * 64 + lane]);
    float xc = bf1(xp2[(size_t)sc_ * 64 + lane]);
    float xd = bf1(xp2[(size_t)sd * 64 + lane]);
    acc += ews[wv][j] * xa + ews[wv][j + 1] * xb + ews[wv][j + 2] * xc + ews[wv][j + 3] * xd;
  }
  for (; i < lim; ++i)
    acc += ews[wv][i - i0] * bf1(xp2[(size_t)csrc[i] * 64 + lane]);
  for (; i < i1; ++i) {
    int sa = csrc[i];
    acc += __expf(lrelu(als[sa] + aldn)) * bf1(xp2[(size_t)sa * 64 + lane]);
  }
  out[(size_t)n * 64 + lane] = acc * inv + b2[lane] + skip[(size_t)n * 64 + lane];
}

// ---------------------------------------------------------------------------
extern "C" void kernel_launch(void* const* d_in, const int* in_sizes, int n_in,
                              void* d_out, int out_size, void* d_ws, size_t ws_size,
                              hipStream_t stream) {
  const float* x_clean = (const float*)d_in[0];
  const float* x_noised = (const float*)d_in[1];
  const int* esrc = (const int*)d_in[2];
  const int* edst = (const int*)d_in[3];
  const float* W1 = (const float*)d_in[4];
  const float* a_src1 = (const float*)d_in[5];
  const float* a_dst1 = (const float*)d_in[6];
  const float* b1 = (const float*)d_in[7];
  const float* W2 = (const float*)d_in[8];
  const float* a_src2 = (const float*)d_in[9];
  const float* a_dst2 = (const float*)d_in[10];
  const float* b2 = (const float*)d_in[11];
  float* out = (float*)d_out;

  const int N = in_sizes[0] / 256;  // 50000
  const int E = in_sizes[2];        // 800000

  unsigned short* W1t = (unsigned short*)d_ws;      // 256*256
  unsigned short* W2t = W1t + 65536;                // 64*256
  unsigned short* xp1 = W2t + 16384;                // N*256 bf16
  unsigned short* hs = xp1 + (size_t)N * 256;       // N*256 bf16 (hs, then h)
  unsigned short* xp2 = hs + (size_t)N * 256;       // N*64 bf16
  float* skip = (float*)(xp2 + (size_t)N * 64);     // N*64 f32
  float* als1 = skip + (size_t)N * 64;              // N*4
  float* ald1 = als1 + (size_t)N * 4;               // N*4
  float* als2 = ald1 + (size_t)N * 4;               // N
  float* ald2 = als2 + N;                           // N
  int* cnt = (int*)(ald2 + N);                      // N
  int* offs = cnt + N;                              // N+1
  int* cur = offs + N + 1;                          // N
  int* csrc = cur + N;                              // E
  int* bsum = csrc + E;                             // <=64
  int* boff = bsum + 64;                            // <=64

  const int gemm_rows = (N + 127) / 128;  // 391
  dim3 block256(256);
  const int wave_grid = (N * 64 + 255) / 256;  // 12500
  const int edge_grid = (E + 255) / 256;
  const int nb = (N + 1023) / 1024;

  hipLaunchKernelGGL(trcvt_kernel, dim3(256), block256, 0, stream, W1, W1t, 256);
  hipLaunchKernelGGL(trcvt_kernel, dim3(64), block256, 0, stream, W2, W2t, 64);
  hipLaunchKernelGGL((gemm_mfma<128, true, false, false, true>), dim3(gemm_rows, 2), block256,
                     0, stream, x_noised, W1t, nullptr, xp1, N, 256);
  hipLaunchKernelGGL((gemm_mfma<128, true, true, true, true>), dim3(gemm_rows, 2), block256,
                     0, stream, x_clean, W1t, b1, hs, N, 256);
  hipLaunchKernelGGL((gemm_mfma<64, false, true, false, false>), dim3(gemm_rows, 1), block256,
                     0, stream, hs, W2t, b2, skip, N, 64);
  hipLaunchKernelGGL(al1_kernel, dim3(wave_grid), block256, 0, stream,
                     xp1, a_src1, a_dst1, als1, ald1, N);
  hipMemsetAsync(cnt, 0, (size_t)N * sizeof(int), stream);
  hipLaunchKernelGGL(count_kernel, dim3(edge_grid), block256, 0, stream, edst, E, cnt);
  hipLaunchKernelGGL(scan_blocks, dim3(nb), block256, 0, stream, cnt, N, offs, bsum);
  hipLaunchKernelGGL(scan_top, dim3(1), dim3(64), 0, stream, bsum, nb, boff, offs, N);
  hipLaunchKernelGGL(scan_add, dim3(nb), block256, 0, stream, offs, cur, boff, N);
  hipLaunchKernelGGL(fill_kernel, dim3(edge_grid), block256, 0, stream, edst, esrc, E, cur, csrc);
  hipLaunchKernelGGL(agg1_kernel, dim3(wave_grid), block256, 0, stream,
                     xp1, als1, ald1, offs, csrc, b1, hs, N);
  hipLaunchKernelGGL((gemm_mfma<64, false, false, false, true>), dim3(gemm_rows, 1), block256,
                     0, stream, hs, W2t, nullptr, xp2, N, 64);
  hipLaunchKernelGGL(al2_kernel, dim3(wave_grid), block256, 0, stream,
                     xp2, a_src2, a_dst2, als2, ald2, N);
  hipLaunchKernelGGL(agg2_kernel, dim3(wave_grid), block256, 0, stream,
                     xp2, als2, ald2, offs, csrc, b2, skip, out, N);
}

// Round 6
// 433.519 us; speedup vs baseline: 2.2491x; 1.0288x over previous
//
#include <hip/hip_runtime.h>
#include <hip/hip_bf16.h>
#include <cstdint>

typedef __bf16 bf16x8 __attribute__((ext_vector_type(8)));
typedef float f32x4 __attribute__((ext_vector_type(4)));

static __device__ __forceinline__ float lrelu(float x) { return x > 0.f ? x : 0.2f * x; }
static __device__ __forceinline__ float bflo(unsigned v) { return __uint_as_float(v << 16); }
static __device__ __forceinline__ float bfhi(unsigned v) { return __uint_as_float(v & 0xffff0000u); }
static __device__ __forceinline__ float bf1(unsigned short v) { return __uint_as_float(((unsigned)v) << 16); }
static __device__ __forceinline__ unsigned short f2bf(float f) {
  unsigned u = __float_as_uint(f);
  u += 0x7fffu + ((u >> 16) & 1u);
  return (unsigned short)(u >> 16);
}

// ---------------------------------------------------------------------------
// bf16 MFMA GEMM: C[M,Nout] = A[M,256] @ W[256,Nout], W pre-transposed bf16.
// AL: fuse attention-logit dot products (als/ald) into the epilogue.
// ---------------------------------------------------------------------------
template <int BN, bool AF32, bool BIAS, bool RELU, bool OUTBF, bool AL>
__global__ __launch_bounds__(256) void gemm_mfma(
    const void* __restrict__ Av, const unsigned short* __restrict__ Bt,
    const float* __restrict__ bias, void* __restrict__ Cv, int M, int Nout,
    const float* __restrict__ asrc, const float* __restrict__ adst,
    float* __restrict__ als, float* __restrict__ ald) {
  constexpr int LDA = 72;
  __shared__ __align__(16) unsigned short Al[128 * LDA];
  __shared__ __align__(16) unsigned short Bl[BN * LDA];
  const int t = threadIdx.x;
  const int w = t >> 6, lane = t & 63;
  const int quad = lane >> 4, l15 = lane & 15;
  const int row0 = blockIdx.x * 128;
  const int c0 = blockIdx.y * BN;
  constexpr int WR = (BN == 128) ? 4 : 2;
  const int wrow0 = (BN == 128) ? (w >> 1) * 64 : w * 32;
  const int wcol0 = (BN == 128) ? (w & 1) * 64 : 0;

  f32x4 acc[WR][4];
#pragma unroll
  for (int i = 0; i < WR; ++i)
#pragma unroll
    for (int j = 0; j < 4; ++j) acc[i][j] = (f32x4){0.f, 0.f, 0.f, 0.f};

  for (int k0 = 0; k0 < 256; k0 += 64) {
#pragma unroll
    for (int ci = 0; ci < 4; ++ci) {
      int id = ci * 256 + t;
      int r = id >> 3, cq = id & 7;
      int gr = row0 + r;
      uint4 pack = make_uint4(0, 0, 0, 0);
      if (AF32) {
        if (gr < M) {
          const float* ap = (const float*)Av + (size_t)gr * 256 + k0 + cq * 8;
          float4 f0 = *(const float4*)ap;
          float4 f1 = *(const float4*)(ap + 4);
          pack.x = (unsigned)f2bf(f0.x) | ((unsigned)f2bf(f0.y) << 16);
          pack.y = (unsigned)f2bf(f0.z) | ((unsigned)f2bf(f0.w) << 16);
          pack.z = (unsigned)f2bf(f1.x) | ((unsigned)f2bf(f1.y) << 16);
          pack.w = (unsigned)f2bf(f1.z) | ((unsigned)f2bf(f1.w) << 16);
        }
      } else {
        if (gr < M)
          pack = *(const uint4*)((const unsigned short*)Av + (size_t)gr * 256 + k0 + cq * 8);
      }
      *(uint4*)&Al[r * LDA + cq * 8] = pack;
    }
#pragma unroll
    for (int ci = 0; ci < BN / 32; ++ci) {
      int id = ci * 256 + t;
      int r = id >> 3, cq = id & 7;
      *(uint4*)&Bl[r * LDA + cq * 8] =
          *(const uint4*)(Bt + (size_t)(c0 + r) * 256 + k0 + cq * 8);
    }
    __syncthreads();
#pragma unroll
    for (int ks = 0; ks < 64; ks += 32) {
      bf16x8 af[WR], bfr[4];
#pragma unroll
      for (int i = 0; i < WR; ++i)
        af[i] = *(const bf16x8*)&Al[(wrow0 + i * 16 + l15) * LDA + ks + quad * 8];
#pragma unroll
      for (int j = 0; j < 4; ++j)
        bfr[j] = *(const bf16x8*)&Bl[(wcol0 + j * 16 + l15) * LDA + ks + quad * 8];
#pragma unroll
      for (int i = 0; i < WR; ++i)
#pragma unroll
        for (int j = 0; j < 4; ++j)
          acc[i][j] = __builtin_amdgcn_mfma_f32_16x16x32_bf16(af[i], bfr[j], acc[i][j], 0, 0, 0);
    }
    __syncthreads();
  }

  if (AL) {
    // this wave's 64 cols form exactly one head; dot with a-vectors, 16-lane reduce.
    const int hidx = (BN == 128) ? ((c0 + wcol0) >> 6) : 0;
    const int hstr = (BN == 128) ? 4 : 1;
    float av[4], dv[4];
#pragma unroll
    for (int j = 0; j < 4; ++j) {
      av[j] = asrc[hidx * 64 + j * 16 + l15];
      dv[j] = adst[hidx * 64 + j * 16 + l15];
    }
#pragma unroll
    for (int i = 0; i < WR; ++i) {
#pragma unroll
      for (int r = 0; r < 4; ++r) {
        float ps = acc[i][0][r] * av[0] + acc[i][1][r] * av[1] +
                   acc[i][2][r] * av[2] + acc[i][3][r] * av[3];
        float pd = acc[i][0][r] * dv[0] + acc[i][1][r] * dv[1] +
                   acc[i][2][r] * dv[2] + acc[i][3][r] * dv[3];
#pragma unroll
        for (int o = 8; o; o >>= 1) {
          ps += __shfl_xor(ps, o, 64);
          pd += __shfl_xor(pd, o, 64);
        }
        int row = row0 + wrow0 + i * 16 + quad * 4 + r;
        if (l15 == 0 && row < M) {
          als[row * hstr + hidx] = ps;
          ald[row * hstr + hidx] = pd;
        }
      }
    }
  }

#pragma unroll
  for (int i = 0; i < WR; ++i) {
#pragma unroll
    for (int j = 0; j < 4; ++j) {
      int col = c0 + wcol0 + j * 16 + l15;
      float bv = BIAS ? bias[col] : 0.f;
#pragma unroll
      for (int r = 0; r < 4; ++r) {
        int row = row0 + wrow0 + i * 16 + quad * 4 + r;
        if (row < M) {
          float v = acc[i][j][r] + bv;
          if (RELU) v = fmaxf(v, 0.f);
          if (OUTBF)
            ((unsigned short*)Cv)[(size_t)row * Nout + col] = f2bf(v);
          else
            ((float*)Cv)[(size_t)row * Nout + col] = v;
        }
      }
    }
  }
}

// transpose-convert both weights in one launch: W1[256,256] and W2[256,64]
__global__ void trcvt_kernel(const float* __restrict__ W1, const float* __restrict__ W2,
                             unsigned short* __restrict__ W1t, unsigned short* __restrict__ W2t) {
  int id = blockIdx.x * blockDim.x + threadIdx.x;
  if (id < 65536) {
    int k = id & 255, n = id >> 8;
    W1t[id] = f2bf(W1[k * 256 + n]);
  } else {
    int id2 = id - 65536;
    int k = id2 & 255, n = id2 >> 8;
    W2t[id2] = f2bf(W2[k * 64 + n]);
  }
}

// ---------------------------------------------------------------------------
// CSR build — hierarchical scan
// ---------------------------------------------------------------------------
__global__ void count_kernel(const int* __restrict__ dst, int E, int* __restrict__ cnt) {
  int e = blockIdx.x * blockDim.x + threadIdx.x;
  if (e < E) atomicAdd(&cnt[dst[e]], 1);
}

__global__ __launch_bounds__(256) void scan_blocks(
    const int* __restrict__ cnt, int n, int* __restrict__ offs, int* __restrict__ bsum) {
  int t = threadIdx.x;
  int base = blockIdx.x * 1024 + t * 4;
  int4 v = make_int4(0, 0, 0, 0);
  if (base + 3 < n) {
    v = *(const int4*)(cnt + base);
  } else {
    if (base + 0 < n) v.x = cnt[base + 0];
    if (base + 1 < n) v.y = cnt[base + 1];
    if (base + 2 < n) v.z = cnt[base + 2];
  }
  int s = v.x + v.y + v.z + v.w;
  int lane = t & 63, w = t >> 6;
  int sc = s;
#pragma unroll
  for (int o = 1; o < 64; o <<= 1) {
    int u = __shfl_up(sc, o, 64);
    if (lane >= o) sc += u;
  }
  __shared__ int wsum[4];
  if (lane == 63) wsum[w] = sc;
  __syncthreads();
  int woff = 0;
#pragma unroll
  for (int i = 0; i < 4; ++i)
    if (i < w) woff += wsum[i];
  int excl = woff + sc - s;
  int o0 = excl, o1 = o0 + v.x, o2 = o1 + v.y, o3 = o2 + v.z;
  if (base + 3 < n) {
    *(int4*)(offs + base) = make_int4(o0, o1, o2, o3);
  } else {
    if (base + 0 < n) offs[base + 0] = o0;
    if (base + 1 < n) offs[base + 1] = o1;
    if (base + 2 < n) offs[base + 2] = o2;
  }
  if (t == 255) bsum[blockIdx.x] = woff + sc;
}

__global__ void scan_top(const int* __restrict__ bsum, int nb, int* __restrict__ boff,
                         int* __restrict__ offs, int n) {
  int lane = threadIdx.x;
  int s = (lane < nb) ? bsum[lane] : 0;
  int sc = s;
#pragma unroll
  for (int o = 1; o < 64; o <<= 1) {
    int u = __shfl_up(sc, o, 64);
    if (lane >= o) sc += u;
  }
  if (lane < nb) boff[lane] = sc - s;
  if (lane == 63) offs[n] = sc;
}

__global__ __launch_bounds__(256) void scan_add(
    int* __restrict__ offs, int* __restrict__ cur, const int* __restrict__ boff, int n) {
  int t = threadIdx.x;
  int base = blockIdx.x * 1024 + t * 4;
  int b = boff[blockIdx.x];
  if (base + 3 < n) {
    int4 v = *(const int4*)(offs + base);
    v.x += b; v.y += b; v.z += b; v.w += b;
    *(int4*)(offs + base) = v;
    *(int4*)(cur + base) = v;
  } else {
    for (int i = 0; i < 4; ++i)
      if (base + i < n) {
        int v = offs[base + i] + b;
        offs[base + i] = v;
        cur[base + i] = v;
      }
  }
}

__global__ void fill_kernel(const int* __restrict__ dst, const int* __restrict__ src, int E,
                            int* __restrict__ cur, int* __restrict__ csrc) {
  int e = blockIdx.x * blockDim.x + threadIdx.x;
  if (e < E) {
    int p = atomicAdd(&cur[dst[e]], 1);
    csrc[p] = src[e];
  }
}

// ---------------------------------------------------------------------------
// agg1 v4: wave per dst node, no max-subtraction (logits bounded),
// pass A: denom + LDS weight stash; pass B: unroll x8 (8 gathers in flight).
// ---------------------------------------------------------------------------
#define CAP1 80
__global__ __launch_bounds__(256) void agg1_kernel(
    const unsigned short* __restrict__ xp, const float* __restrict__ als,
    const float* __restrict__ ald, const int* __restrict__ offs,
    const int* __restrict__ csrc, const float* __restrict__ b1,
    unsigned short* __restrict__ hout, int nn) {
  __shared__ float ews[4][CAP1 * 4];
  int wv = threadIdx.x >> 6;
  int n = (blockIdx.x * blockDim.x + threadIdx.x) >> 6;
  int lane = threadIdx.x & 63;
  if (n >= nn) return;
  float4 aldn = *(const float4*)(ald + (size_t)n * 4);
  float4 alsn = *(const float4*)(als + (size_t)n * 4);
  float w0 = __expf(lrelu(alsn.x + aldn.x)), w1 = __expf(lrelu(alsn.y + aldn.y));
  float w2 = __expf(lrelu(alsn.z + aldn.z)), w3 = __expf(lrelu(alsn.w + aldn.w));
  int i0 = offs[n], i1 = offs[n + 1];

  float d0 = 0.f, d1 = 0.f, d2 = 0.f, d3 = 0.f;
  for (int i = i0 + lane; i < i1; i += 64) {
    int s = csrc[i];
    float4 a4 = *(const float4*)(als + (size_t)s * 4);
    float e0 = __expf(lrelu(a4.x + aldn.x));
    float e1 = __expf(lrelu(a4.y + aldn.y));
    float e2 = __expf(lrelu(a4.z + aldn.z));
    float e3 = __expf(lrelu(a4.w + aldn.w));
    d0 += e0; d1 += e1; d2 += e2; d3 += e3;
    int j = i - i0;
    if (j < CAP1) *(float4*)&ews[wv][j * 4] = make_float4(e0, e1, e2, e3);
  }
#pragma unroll
  for (int o = 32; o; o >>= 1) {
    d0 += __shfl_xor(d0, o, 64);
    d1 += __shfl_xor(d1, o, 64);
    d2 += __shfl_xor(d2, o, 64);
    d3 += __shfl_xor(d3, o, 64);
  }
  d0 += w0; d1 += w1; d2 += w2; d3 += w3;

  int h = lane >> 4;
  float selfw = (h == 0) ? w0 : (h == 1) ? w1 : (h == 2) ? w2 : w3;
  float invh = 1.f / ((h == 0) ? d0 : (h == 1) ? d1 : (h == 2) ? d2 : d3);
  float adh = (h == 0) ? aldn.x : (h == 1) ? aldn.y : (h == 2) ? aldn.z : aldn.w;

  uint2 v = *(const uint2*)(xp + (size_t)n * 256 + lane * 4);
  float a0 = selfw * bflo(v.x), a1 = selfw * bfhi(v.x);
  float a2 = selfw * bflo(v.y), a3 = selfw * bfhi(v.y);

  int lim = min(i1, i0 + CAP1);
  int i = i0;
  for (; i + 7 < lim; i += 8) {
    int j = i - i0;
    uint2 u[8];
    float wt[8];
#pragma unroll
    for (int q = 0; q < 8; ++q) {
      int s = csrc[i + q];
      u[q] = *(const uint2*)(xp + (size_t)s * 256 + lane * 4);
    }
#pragma unroll
    for (int q = 0; q < 8; ++q) wt[q] = ews[wv][(j + q) * 4 + h];
#pragma unroll
    for (int q = 0; q < 8; ++q) {
      a0 += wt[q] * bflo(u[q].x); a1 += wt[q] * bfhi(u[q].x);
      a2 += wt[q] * bflo(u[q].y); a3 += wt[q] * bfhi(u[q].y);
    }
  }
  for (; i < lim; ++i) {
    int sa = csrc[i];
    uint2 ua = *(const uint2*)(xp + (size_t)sa * 256 + lane * 4);
    float wa = ews[wv][(i - i0) * 4 + h];
    a0 += wa * bflo(ua.x); a1 += wa * bfhi(ua.x);
    a2 += wa * bflo(ua.y); a3 += wa * bfhi(ua.y);
  }
  for (; i < i1; ++i) {  // cold tail: deg > CAP1
    int sa = csrc[i];
    uint2 ua = *(const uint2*)(xp + (size_t)sa * 256 + lane * 4);
    float wa = __expf(lrelu(als[(size_t)sa * 4 + h] + adh));
    a0 += wa * bflo(ua.x); a1 += wa * bfhi(ua.x);
    a2 += wa * bflo(ua.y); a3 += wa * bfhi(ua.y);
  }
  float4 bb = *(const float4*)(b1 + lane * 4);
  float o0 = a0 * invh + bb.x, o1 = a1 * invh + bb.y;
  float o2 = a2 * invh + bb.z, o3 = a3 * invh + bb.w;
  o0 = o0 > 0.f ? o0 : __expf(o0) - 1.f;
  o1 = o1 > 0.f ? o1 : __expf(o1) - 1.f;
  o2 = o2 > 0.f ? o2 : __expf(o2) - 1.f;
  o3 = o3 > 0.f ? o3 : __expf(o3) - 1.f;
  uint2 p;
  p.x = (unsigned)f2bf(o0) | ((unsigned)f2bf(o1) << 16);
  p.y = (unsigned)f2bf(o2) | ((unsigned)f2bf(o3) << 16);
  *(uint2*)(hout + (size_t)n * 256 + lane * 4) = p;
}

// agg2 v4: same structure, 1 head, unroll x8, fuse +b2 +skip.
#define CAP2 128
__global__ __launch_bounds__(256) void agg2_kernel(
    const unsigned short* __restrict__ xp2, const float* __restrict__ als,
    const float* __restrict__ ald, const int* __restrict__ offs,
    const int* __restrict__ csrc, const float* __restrict__ b2,
    const float* __restrict__ skip, float* __restrict__ out, int nn) {
  __shared__ float ews[4][CAP2];
  int wv = threadIdx.x >> 6;
  int n = (blockIdx.x * blockDim.x + threadIdx.x) >> 6;
  int lane = threadIdx.x & 63;
  if (n >= nn) return;
  float aldn = ald[n];
  float selfw = __expf(lrelu(als[n] + aldn));
  int i0 = offs[n], i1 = offs[n + 1];

  float d = 0.f;
  for (int i = i0 + lane; i < i1; i += 64) {
    float e = __expf(lrelu(als[csrc[i]] + aldn));
    d += e;
    int j = i - i0;
    if (j < CAP2) ews[wv][j] = e;
  }
#pragma unroll
  for (int o = 32; o; o >>= 1) d += __shfl_xor(d, o, 64);
  d += selfw;
  float inv = 1.f / d;

  float acc = selfw * bf1(xp2[(size_t)n * 64 + lane]);
  int lim = min(i1, i0 + CAP2);
  int i = i0;
  for (; i + 7 < lim; i += 8) {
    int j = i - i0;
    float x[8];
#pragma unroll
    for (int q = 0; q < 8; ++q)
      x[q] = bf1(xp2[(size_t)csrc[i + q] * 64 + lane]);
#pragma unroll
    for (int q = 0; q < 8; ++q) acc += ews[wv][j + q] * x[q];
  }
  for (; i < lim; ++i)
    acc += ews[wv][i - i0] * bf1(xp2[(size_t)csrc[i] * 64 + lane]);
  for (; i < i1; ++i) {
    int sa = csrc[i];
    acc += __expf(lrelu(als[sa] + aldn)) * bf1(xp2[(size_t)sa * 64 + lane]);
  }
  out[(size_t)n * 64 + lane] = acc * inv + b2[lane] + skip[(size_t)n * 64 + lane];
}

// ---------------------------------------------------------------------------
extern "C" void kernel_launch(void* const* d_in, const int* in_sizes, int n_in,
                              void* d_out, int out_size, void* d_ws, size_t ws_size,
                              hipStream_t stream) {
  const float* x_clean = (const float*)d_in[0];
  const float* x_noised = (const float*)d_in[1];
  const int* esrc = (const int*)d_in[2];
  const int* edst = (const int*)d_in[3];
  const float* W1 = (const float*)d_in[4];
  const float* a_src1 = (const float*)d_in[5];
  const float* a_dst1 = (const float*)d_in[6];
  const float* b1 = (const float*)d_in[7];
  const float* W2 = (const float*)d_in[8];
  const float* a_src2 = (const float*)d_in[9];
  const float* a_dst2 = (const float*)d_in[10];
  const float* b2 = (const float*)d_in[11];
  float* out = (float*)d_out;

  const int N = in_sizes[0] / 256;  // 50000
  const int E = in_sizes[2];        // 800000

  unsigned short* W1t = (unsigned short*)d_ws;      // 256*256
  unsigned short* W2t = W1t + 65536;                // 64*256
  unsigned short* xp1 = W2t + 16384;                // N*256 bf16
  unsigned short* hs = xp1 + (size_t)N * 256;       // N*256 bf16 (hs, then h)
  unsigned short* xp2 = hs + (size_t)N * 256;       // N*64 bf16
  float* skip = (float*)(xp2 + (size_t)N * 64);     // N*64 f32
  float* als1 = skip + (size_t)N * 64;              // N*4
  float* ald1 = als1 + (size_t)N * 4;               // N*4
  float* als2 = ald1 + (size_t)N * 4;               // N
  float* ald2 = als2 + N;                           // N
  int* cnt = (int*)(ald2 + N);                      // N
  int* offs = cnt + N;                              // N+1
  int* cur = offs + N + 1;                          // N
  int* csrc = cur + N;                              // E
  int* bsum = csrc + E;                             // <=64
  int* boff = bsum + 64;                            // <=64

  const int gemm_rows = (N + 127) / 128;  // 391
  dim3 block256(256);
  const int wave_grid = (N * 64 + 255) / 256;  // 12500
  const int edge_grid = (E + 255) / 256;
  const int nb = (N + 1023) / 1024;

  hipLaunchKernelGGL(trcvt_kernel, dim3((65536 + 16384) / 256), block256, 0, stream,
                     W1, W2, W1t, W2t);
  // xp1 = x_noised @ W1 (bf16 out) + fused al1
  hipLaunchKernelGGL((gemm_mfma<128, true, false, false, true, true>), dim3(gemm_rows, 2),
                     block256, 0, stream, x_noised, W1t, nullptr, xp1, N, 256,
                     a_src1, a_dst1, als1, ald1);
  // hs = relu(x_clean @ W1 + b1)
  hipLaunchKernelGGL((gemm_mfma<128, true, true, true, true, false>), dim3(gemm_rows, 2),
                     block256, 0, stream, x_clean, W1t, b1, hs, N, 256,
                     nullptr, nullptr, nullptr, nullptr);
  // skip = hs @ W2 + b2 (fp32 out)
  hipLaunchKernelGGL((gemm_mfma<64, false, true, false, false, false>), dim3(gemm_rows, 1),
                     block256, 0, stream, hs, W2t, b2, skip, N, 64,
                     nullptr, nullptr, nullptr, nullptr);
  // CSR build
  hipMemsetAsync(cnt, 0, (size_t)N * sizeof(int), stream);
  hipLaunchKernelGGL(count_kernel, dim3(edge_grid), block256, 0, stream, edst, E, cnt);
  hipLaunchKernelGGL(scan_blocks, dim3(nb), block256, 0, stream, cnt, N, offs, bsum);
  hipLaunchKernelGGL(scan_top, dim3(1), dim3(64), 0, stream, bsum, nb, boff, offs, N);
  hipLaunchKernelGGL(scan_add, dim3(nb), block256, 0, stream, offs, cur, boff, N);
  hipLaunchKernelGGL(fill_kernel, dim3(edge_grid), block256, 0, stream, edst, esrc, E, cur, csrc);
  // layer-1 aggregation -> h
  hipLaunchKernelGGL(agg1_kernel, dim3(wave_grid), block256, 0, stream,
                     xp1, als1, ald1, offs, csrc, b1, hs, N);
  // xp2 = h @ W2 (bf16 out) + fused al2
  hipLaunchKernelGGL((gemm_mfma<64, false, false, false, true, true>), dim3(gemm_rows, 1),
                     block256, 0, stream, hs, W2t, nullptr, xp2, N, 64,
                     a_src2, a_dst2, als2, ald2);
  // layer-2 aggregation + b2 + skip -> out
  hipLaunchKernelGGL(agg2_kernel, dim3(wave_grid), block256, 0, stream,
                     xp2, als2, ald2, offs, csrc, b2, skip, out, N);
}

// Round 7
// 427.055 us; speedup vs baseline: 2.2831x; 1.0151x over previous
//
#include <hip/hip_runtime.h>
#include <hip/hip_bf16.h>
#include <cstdint>

typedef __bf16 bf16x8 __attribute__((ext_vector_type(8)));
typedef float f32x4 __attribute__((ext_vector_type(4)));

static __device__ __forceinline__ float lrelu(float x) { return x > 0.f ? x : 0.2f * x; }
static __device__ __forceinline__ float bflo(unsigned v) { return __uint_as_float(v << 16); }
static __device__ __forceinline__ float bfhi(unsigned v) { return __uint_as_float(v & 0xffff0000u); }
static __device__ __forceinline__ float bf1(unsigned short v) { return __uint_as_float(((unsigned)v) << 16); }
static __device__ __forceinline__ unsigned short f2bf(float f) {
  unsigned u = __float_as_uint(f);
  u += 0x7fffu + ((u >> 16) & 1u);
  return (unsigned short)(u >> 16);
}

// ---------------------------------------------------------------------------
// bf16 MFMA GEMM: C[M,Nout] = A[M,256] @ W[256,Nout], W pre-transposed bf16.
// AL: fuse attention-logit dot products (als/ald) into the epilogue.
// ---------------------------------------------------------------------------
template <int BN, bool AF32, bool BIAS, bool RELU, bool OUTBF, bool AL>
__global__ __launch_bounds__(256) void gemm_mfma(
    const void* __restrict__ Av, const unsigned short* __restrict__ Bt,
    const float* __restrict__ bias, void* __restrict__ Cv, int M, int Nout,
    const float* __restrict__ asrc, const float* __restrict__ adst,
    float* __restrict__ als, float* __restrict__ ald) {
  constexpr int LDA = 72;
  __shared__ __align__(16) unsigned short Al[128 * LDA];
  __shared__ __align__(16) unsigned short Bl[BN * LDA];
  const int t = threadIdx.x;
  const int w = t >> 6, lane = t & 63;
  const int quad = lane >> 4, l15 = lane & 15;
  const int row0 = blockIdx.x * 128;
  const int c0 = blockIdx.y * BN;
  constexpr int WR = (BN == 128) ? 4 : 2;
  const int wrow0 = (BN == 128) ? (w >> 1) * 64 : w * 32;
  const int wcol0 = (BN == 128) ? (w & 1) * 64 : 0;

  f32x4 acc[WR][4];
#pragma unroll
  for (int i = 0; i < WR; ++i)
#pragma unroll
    for (int j = 0; j < 4; ++j) acc[i][j] = (f32x4){0.f, 0.f, 0.f, 0.f};

  for (int k0 = 0; k0 < 256; k0 += 64) {
#pragma unroll
    for (int ci = 0; ci < 4; ++ci) {
      int id = ci * 256 + t;
      int r = id >> 3, cq = id & 7;
      int gr = row0 + r;
      uint4 pack = make_uint4(0, 0, 0, 0);
      if (AF32) {
        if (gr < M) {
          const float* ap = (const float*)Av + (size_t)gr * 256 + k0 + cq * 8;
          float4 f0 = *(const float4*)ap;
          float4 f1 = *(const float4*)(ap + 4);
          pack.x = (unsigned)f2bf(f0.x) | ((unsigned)f2bf(f0.y) << 16);
          pack.y = (unsigned)f2bf(f0.z) | ((unsigned)f2bf(f0.w) << 16);
          pack.z = (unsigned)f2bf(f1.x) | ((unsigned)f2bf(f1.y) << 16);
          pack.w = (unsigned)f2bf(f1.z) | ((unsigned)f2bf(f1.w) << 16);
        }
      } else {
        if (gr < M)
          pack = *(const uint4*)((const unsigned short*)Av + (size_t)gr * 256 + k0 + cq * 8);
      }
      *(uint4*)&Al[r * LDA + cq * 8] = pack;
    }
#pragma unroll
    for (int ci = 0; ci < BN / 32; ++ci) {
      int id = ci * 256 + t;
      int r = id >> 3, cq = id & 7;
      *(uint4*)&Bl[r * LDA + cq * 8] =
          *(const uint4*)(Bt + (size_t)(c0 + r) * 256 + k0 + cq * 8);
    }
    __syncthreads();
#pragma unroll
    for (int ks = 0; ks < 64; ks += 32) {
      bf16x8 af[WR], bfr[4];
#pragma unroll
      for (int i = 0; i < WR; ++i)
        af[i] = *(const bf16x8*)&Al[(wrow0 + i * 16 + l15) * LDA + ks + quad * 8];
#pragma unroll
      for (int j = 0; j < 4; ++j)
        bfr[j] = *(const bf16x8*)&Bl[(wcol0 + j * 16 + l15) * LDA + ks + quad * 8];
#pragma unroll
      for (int i = 0; i < WR; ++i)
#pragma unroll
        for (int j = 0; j < 4; ++j)
          acc[i][j] = __builtin_amdgcn_mfma_f32_16x16x32_bf16(af[i], bfr[j], acc[i][j], 0, 0, 0);
    }
    __syncthreads();
  }

  if (AL) {
    const int hidx = (BN == 128) ? ((c0 + wcol0) >> 6) : 0;
    const int hstr = (BN == 128) ? 4 : 1;
    float av[4], dv[4];
#pragma unroll
    for (int j = 0; j < 4; ++j) {
      av[j] = asrc[hidx * 64 + j * 16 + l15];
      dv[j] = adst[hidx * 64 + j * 16 + l15];
    }
#pragma unroll
    for (int i = 0; i < WR; ++i) {
#pragma unroll
      for (int r = 0; r < 4; ++r) {
        float ps = acc[i][0][r] * av[0] + acc[i][1][r] * av[1] +
                   acc[i][2][r] * av[2] + acc[i][3][r] * av[3];
        float pd = acc[i][0][r] * dv[0] + acc[i][1][r] * dv[1] +
                   acc[i][2][r] * dv[2] + acc[i][3][r] * dv[3];
#pragma unroll
        for (int o = 8; o; o >>= 1) {
          ps += __shfl_xor(ps, o, 64);
          pd += __shfl_xor(pd, o, 64);
        }
        int row = row0 + wrow0 + i * 16 + quad * 4 + r;
        if (l15 == 0 && row < M) {
          als[row * hstr + hidx] = ps;
          ald[row * hstr + hidx] = pd;
        }
      }
    }
  }

#pragma unroll
  for (int i = 0; i < WR; ++i) {
#pragma unroll
    for (int j = 0; j < 4; ++j) {
      int col = c0 + wcol0 + j * 16 + l15;
      float bv = BIAS ? bias[col] : 0.f;
#pragma unroll
      for (int r = 0; r < 4; ++r) {
        int row = row0 + wrow0 + i * 16 + quad * 4 + r;
        if (row < M) {
          float v = acc[i][j][r] + bv;
          if (RELU) v = fmaxf(v, 0.f);
          if (OUTBF)
            ((unsigned short*)Cv)[(size_t)row * Nout + col] = f2bf(v);
          else
            ((float*)Cv)[(size_t)row * Nout + col] = v;
        }
      }
    }
  }
}

__global__ void trcvt_kernel(const float* __restrict__ W1, const float* __restrict__ W2,
                             unsigned short* __restrict__ W1t, unsigned short* __restrict__ W2t) {
  int id = blockIdx.x * blockDim.x + threadIdx.x;
  if (id < 65536) {
    int k = id & 255, n = id >> 8;
    W1t[id] = f2bf(W1[k * 256 + n]);
  } else {
    int id2 = id - 65536;
    int k = id2 & 255, n = id2 >> 8;
    W2t[id2] = f2bf(W2[k * 64 + n]);
  }
}

// ---------------------------------------------------------------------------
// CSR build — hierarchical scan
// ---------------------------------------------------------------------------
__global__ void count_kernel(const int* __restrict__ dst, int E, int* __restrict__ cnt) {
  int e = blockIdx.x * blockDim.x + threadIdx.x;
  if (e < E) atomicAdd(&cnt[dst[e]], 1);
}

__global__ __launch_bounds__(256) void scan_blocks(
    const int* __restrict__ cnt, int n, int* __restrict__ offs, int* __restrict__ bsum) {
  int t = threadIdx.x;
  int base = blockIdx.x * 1024 + t * 4;
  int4 v = make_int4(0, 0, 0, 0);
  if (base + 3 < n) {
    v = *(const int4*)(cnt + base);
  } else {
    if (base + 0 < n) v.x = cnt[base + 0];
    if (base + 1 < n) v.y = cnt[base + 1];
    if (base + 2 < n) v.z = cnt[base + 2];
  }
  int s = v.x + v.y + v.z + v.w;
  int lane = t & 63, w = t >> 6;
  int sc = s;
#pragma unroll
  for (int o = 1; o < 64; o <<= 1) {
    int u = __shfl_up(sc, o, 64);
    if (lane >= o) sc += u;
  }
  __shared__ int wsum[4];
  if (lane == 63) wsum[w] = sc;
  __syncthreads();
  int woff = 0;
#pragma unroll
  for (int i = 0; i < 4; ++i)
    if (i < w) woff += wsum[i];
  int excl = woff + sc - s;
  int o0 = excl, o1 = o0 + v.x, o2 = o1 + v.y, o3 = o2 + v.z;
  if (base + 3 < n) {
    *(int4*)(offs + base) = make_int4(o0, o1, o2, o3);
  } else {
    if (base + 0 < n) offs[base + 0] = o0;
    if (base + 1 < n) offs[base + 1] = o1;
    if (base + 2 < n) offs[base + 2] = o2;
  }
  if (t == 255) bsum[blockIdx.x] = woff + sc;
}

__global__ void scan_top(const int* __restrict__ bsum, int nb, int* __restrict__ boff,
                         int* __restrict__ offs, int n) {
  int lane = threadIdx.x;
  int s = (lane < nb) ? bsum[lane] : 0;
  int sc = s;
#pragma unroll
  for (int o = 1; o < 64; o <<= 1) {
    int u = __shfl_up(sc, o, 64);
    if (lane >= o) sc += u;
  }
  if (lane < nb) boff[lane] = sc - s;
  if (lane == 63) offs[n] = sc;
}

__global__ __launch_bounds__(256) void scan_add(
    int* __restrict__ offs, int* __restrict__ cur, const int* __restrict__ boff, int n) {
  int t = threadIdx.x;
  int base = blockIdx.x * 1024 + t * 4;
  int b = boff[blockIdx.x];
  if (base + 3 < n) {
    int4 v = *(const int4*)(offs + base);
    v.x += b; v.y += b; v.z += b; v.w += b;
    *(int4*)(offs + base) = v;
    *(int4*)(cur + base) = v;
  } else {
    for (int i = 0; i < 4; ++i)
      if (base + i < n) {
        int v = offs[base + i] + b;
        offs[base + i] = v;
        cur[base + i] = v;
      }
  }
}

__global__ void fill_kernel(const int* __restrict__ dst, const int* __restrict__ src, int E,
                            int* __restrict__ cur, int* __restrict__ csrc) {
  int e = blockIdx.x * blockDim.x + threadIdx.x;
  if (e < E) {
    int p = atomicAdd(&cur[dst[e]], 1);
    csrc[p] = src[e];
  }
}

// ---------------------------------------------------------------------------
// agg1 v5: wave per dst node. Pass A: 64-lane denom + LDS weight stash.
// Pass B: 2 edges per wave-iteration — lanes 0-31 even edges, 32-63 odd
// edges, 16B/lane (8 channels); final shfl_xor(32) merges halves.
// ---------------------------------------------------------------------------
#define CAP1 80
__global__ __launch_bounds__(256) void agg1_kernel(
    const unsigned short* __restrict__ xp, const float* __restrict__ als,
    const float* __restrict__ ald, const int* __restrict__ offs,
    const int* __restrict__ csrc, const float* __restrict__ b1,
    unsigned short* __restrict__ hout, int nn) {
  __shared__ float ews[4][CAP1 * 4];
  int wv = threadIdx.x >> 6;
  int n = (blockIdx.x * blockDim.x + threadIdx.x) >> 6;
  int lane = threadIdx.x & 63;
  if (n >= nn) return;
  float4 aldn = *(const float4*)(ald + (size_t)n * 4);
  float4 alsn = *(const float4*)(als + (size_t)n * 4);
  float w0 = __expf(lrelu(alsn.x + aldn.x)), w1 = __expf(lrelu(alsn.y + aldn.y));
  float w2 = __expf(lrelu(alsn.z + aldn.z)), w3 = __expf(lrelu(alsn.w + aldn.w));
  int i0 = offs[n], i1 = offs[n + 1];

  // pass A: denom + weight stash (64-lane parallel over edges)
  float d0 = 0.f, d1 = 0.f, d2 = 0.f, d3 = 0.f;
  for (int i = i0 + lane; i < i1; i += 64) {
    int s = csrc[i];
    float4 a4 = *(const float4*)(als + (size_t)s * 4);
    float e0 = __expf(lrelu(a4.x + aldn.x));
    float e1 = __expf(lrelu(a4.y + aldn.y));
    float e2 = __expf(lrelu(a4.z + aldn.z));
    float e3 = __expf(lrelu(a4.w + aldn.w));
    d0 += e0; d1 += e1; d2 += e2; d3 += e3;
    int j = i - i0;
    if (j < CAP1) *(float4*)&ews[wv][j * 4] = make_float4(e0, e1, e2, e3);
  }
#pragma unroll
  for (int o = 32; o; o >>= 1) {
    d0 += __shfl_xor(d0, o, 64);
    d1 += __shfl_xor(d1, o, 64);
    d2 += __shfl_xor(d2, o, 64);
    d3 += __shfl_xor(d3, o, 64);
  }
  d0 += w0; d1 += w1; d2 += w2; d3 += w3;

  // pass B: half-wave per edge, 16B/lane (8 channels, head = l32>>3)
  int half = lane >> 5, l32 = lane & 31;
  int hh = l32 >> 3;
  float selfw = (hh == 0) ? w0 : (hh == 1) ? w1 : (hh == 2) ? w2 : w3;
  float invh = 1.f / ((hh == 0) ? d0 : (hh == 1) ? d1 : (hh == 2) ? d2 : d3);
  float adh = (hh == 0) ? aldn.x : (hh == 1) ? aldn.y : (hh == 2) ? aldn.z : aldn.w;

  uint4 sv = *(const uint4*)(xp + (size_t)n * 256 + l32 * 8);
  float sw = (half == 0) ? selfw : 0.f;
  float a0 = sw * bflo(sv.x), a1 = sw * bfhi(sv.x);
  float a2 = sw * bflo(sv.y), a3 = sw * bfhi(sv.y);
  float a4 = sw * bflo(sv.z), a5 = sw * bfhi(sv.z);
  float a6 = sw * bflo(sv.w), a7 = sw * bfhi(sv.w);

  int lim = min(i1, i0 + CAP1);
  int i = i0 + half;
  for (; i + 6 < lim; i += 8) {  // 4 pairs unrolled: this half does i,i+2,i+4,i+6
    uint4 u[4];
    float wt[4];
#pragma unroll
    for (int q = 0; q < 4; ++q) {
      int s = csrc[i + q * 2];
      u[q] = *(const uint4*)(xp + (size_t)s * 256 + l32 * 8);
    }
#pragma unroll
    for (int q = 0; q < 4; ++q) wt[q] = ews[wv][(i + q * 2 - i0) * 4 + hh];
#pragma unroll
    for (int q = 0; q < 4; ++q) {
      a0 += wt[q] * bflo(u[q].x); a1 += wt[q] * bfhi(u[q].x);
      a2 += wt[q] * bflo(u[q].y); a3 += wt[q] * bfhi(u[q].y);
      a4 += wt[q] * bflo(u[q].z); a5 += wt[q] * bfhi(u[q].z);
      a6 += wt[q] * bflo(u[q].w); a7 += wt[q] * bfhi(u[q].w);
    }
  }
  for (; i < lim; i += 2) {
    int s = csrc[i];
    uint4 u = *(const uint4*)(xp + (size_t)s * 256 + l32 * 8);
    float wt = ews[wv][(i - i0) * 4 + hh];
    a0 += wt * bflo(u.x); a1 += wt * bfhi(u.x);
    a2 += wt * bflo(u.y); a3 += wt * bfhi(u.y);
    a4 += wt * bflo(u.z); a5 += wt * bfhi(u.z);
    a6 += wt * bflo(u.w); a7 += wt * bfhi(u.w);
  }
  for (; i < i1; i += 2) {  // cold tail: deg > CAP1
    int s = csrc[i];
    uint4 u = *(const uint4*)(xp + (size_t)s * 256 + l32 * 8);
    float wt = __expf(lrelu(als[(size_t)s * 4 + hh] + adh));
    a0 += wt * bflo(u.x); a1 += wt * bfhi(u.x);
    a2 += wt * bflo(u.y); a3 += wt * bfhi(u.y);
    a4 += wt * bflo(u.z); a5 += wt * bfhi(u.z);
    a6 += wt * bflo(u.w); a7 += wt * bfhi(u.w);
  }
  // merge halves
  a0 += __shfl_xor(a0, 32, 64); a1 += __shfl_xor(a1, 32, 64);
  a2 += __shfl_xor(a2, 32, 64); a3 += __shfl_xor(a3, 32, 64);
  a4 += __shfl_xor(a4, 32, 64); a5 += __shfl_xor(a5, 32, 64);
  a6 += __shfl_xor(a6, 32, 64); a7 += __shfl_xor(a7, 32, 64);
  if (half == 0) {
    float4 bb0 = *(const float4*)(b1 + l32 * 8);
    float4 bb1 = *(const float4*)(b1 + l32 * 8 + 4);
    float o0 = a0 * invh + bb0.x, o1 = a1 * invh + bb0.y;
    float o2 = a2 * invh + bb0.z, o3 = a3 * invh + bb0.w;
    float o4 = a4 * invh + bb1.x, o5 = a5 * invh + bb1.y;
    float o6 = a6 * invh + bb1.z, o7 = a7 * invh + bb1.w;
    o0 = o0 > 0.f ? o0 : __expf(o0) - 1.f;
    o1 = o1 > 0.f ? o1 : __expf(o1) - 1.f;
    o2 = o2 > 0.f ? o2 : __expf(o2) - 1.f;
    o3 = o3 > 0.f ? o3 : __expf(o3) - 1.f;
    o4 = o4 > 0.f ? o4 : __expf(o4) - 1.f;
    o5 = o5 > 0.f ? o5 : __expf(o5) - 1.f;
    o6 = o6 > 0.f ? o6 : __expf(o6) - 1.f;
    o7 = o7 > 0.f ? o7 : __expf(o7) - 1.f;
    uint4 p;
    p.x = (unsigned)f2bf(o0) | ((unsigned)f2bf(o1) << 16);
    p.y = (unsigned)f2bf(o2) | ((unsigned)f2bf(o3) << 16);
    p.z = (unsigned)f2bf(o4) | ((unsigned)f2bf(o5) << 16);
    p.w = (unsigned)f2bf(o6) | ((unsigned)f2bf(o7) << 16);
    *(uint4*)(hout + (size_t)n * 256 + l32 * 8) = p;
  }
}

// agg2 v5: 4 edges per wave-iteration — 16-lane groups, 8B/lane (4 ch);
// merge via shfl_xor(16)+(32); fuse +b2 +skip.
#define CAP2 128
__global__ __launch_bounds__(256) void agg2_kernel(
    const unsigned short* __restrict__ xp2, const float* __restrict__ als,
    const float* __restrict__ ald, const int* __restrict__ offs,
    const int* __restrict__ csrc, const float* __restrict__ b2,
    const float* __restrict__ skip, float* __restrict__ out, int nn) {
  __shared__ float ews[4][CAP2];
  int wv = threadIdx.x >> 6;
  int n = (blockIdx.x * blockDim.x + threadIdx.x) >> 6;
  int lane = threadIdx.x & 63;
  if (n >= nn) return;
  float aldn = ald[n];
  float selfw = __expf(lrelu(als[n] + aldn));
  int i0 = offs[n], i1 = offs[n + 1];

  float d = 0.f;
  for (int i = i0 + lane; i < i1; i += 64) {
    float e = __expf(lrelu(als[csrc[i]] + aldn));
    d += e;
    int j = i - i0;
    if (j < CAP2) ews[wv][j] = e;
  }
#pragma unroll
  for (int o = 32; o; o >>= 1) d += __shfl_xor(d, o, 64);
  d += selfw;
  float inv = 1.f / d;

  int grp = lane >> 4, l16 = lane & 15;
  uint2 sv = *(const uint2*)(xp2 + (size_t)n * 64 + l16 * 4);
  float sw = (grp == 0) ? selfw : 0.f;
  float a0 = sw * bflo(sv.x), a1 = sw * bfhi(sv.x);
  float a2 = sw * bflo(sv.y), a3 = sw * bfhi(sv.y);

  int lim = min(i1, i0 + CAP2);
  int i = i0 + grp;
  for (; i + 12 < lim; i += 16) {  // 4 quads unrolled
    uint2 u[4];
    float wt[4];
#pragma unroll
    for (int q = 0; q < 4; ++q) {
      int s = csrc[i + q * 4];
      u[q] = *(const uint2*)(xp2 + (size_t)s * 64 + l16 * 4);
    }
#pragma unroll
    for (int q = 0; q < 4; ++q) wt[q] = ews[wv][i + q * 4 - i0];
#pragma unroll
    for (int q = 0; q < 4; ++q) {
      a0 += wt[q] * bflo(u[q].x); a1 += wt[q] * bfhi(u[q].x);
      a2 += wt[q] * bflo(u[q].y); a3 += wt[q] * bfhi(u[q].y);
    }
  }
  for (; i < lim; i += 4) {
    int s = csrc[i];
    uint2 u = *(const uint2*)(xp2 + (size_t)s * 64 + l16 * 4);
    float wt = ews[wv][i - i0];
    a0 += wt * bflo(u.x); a1 += wt * bfhi(u.x);
    a2 += wt * bflo(u.y); a3 += wt * bfhi(u.y);
  }
  for (; i < i1; i += 4) {  // cold tail
    int s = csrc[i];
    uint2 u = *(const uint2*)(xp2 + (size_t)s * 64 + l16 * 4);
    float wt = __expf(lrelu(als[s] + aldn));
    a0 += wt * bflo(u.x); a1 += wt * bfhi(u.x);
    a2 += wt * bflo(u.y); a3 += wt * bfhi(u.y);
  }
#pragma unroll
  for (int o = 16; o <= 32; o <<= 1) {
    a0 += __shfl_xor(a0, o, 64); a1 += __shfl_xor(a1, o, 64);
    a2 += __shfl_xor(a2, o, 64); a3 += __shfl_xor(a3, o, 64);
  }
  if (grp == 0) {
    float4 bb = *(const float4*)(b2 + l16 * 4);
    float4 sk = *(const float4*)(skip + (size_t)n * 64 + l16 * 4);
    float4 o4;
    o4.x = a0 * inv + bb.x + sk.x;
    o4.y = a1 * inv + bb.y + sk.y;
    o4.z = a2 * inv + bb.z + sk.z;
    o4.w = a3 * inv + bb.w + sk.w;
    *(float4*)(out + (size_t)n * 64 + l16 * 4) = o4;
  }
}

// ---------------------------------------------------------------------------
extern "C" void kernel_launch(void* const* d_in, const int* in_sizes, int n_in,
                              void* d_out, int out_size, void* d_ws, size_t ws_size,
                              hipStream_t stream) {
  const float* x_clean = (const float*)d_in[0];
  const float* x_noised = (const float*)d_in[1];
  const int* esrc = (const int*)d_in[2];
  const int* edst = (const int*)d_in[3];
  const float* W1 = (const float*)d_in[4];
  const float* a_src1 = (const float*)d_in[5];
  const float* a_dst1 = (const float*)d_in[6];
  const float* b1 = (const float*)d_in[7];
  const float* W2 = (const float*)d_in[8];
  const float* a_src2 = (const float*)d_in[9];
  const float* a_dst2 = (const float*)d_in[10];
  const float* b2 = (const float*)d_in[11];
  float* out = (float*)d_out;

  const int N = in_sizes[0] / 256;  // 50000
  const int E = in_sizes[2];        // 800000

  unsigned short* W1t = (unsigned short*)d_ws;      // 256*256
  unsigned short* W2t = W1t + 65536;                // 64*256
  unsigned short* xp1 = W2t + 16384;                // N*256 bf16
  unsigned short* hs = xp1 + (size_t)N * 256;       // N*256 bf16 (hs, then h)
  unsigned short* xp2 = hs + (size_t)N * 256;       // N*64 bf16
  float* skip = (float*)(xp2 + (size_t)N * 64);     // N*64 f32
  float* als1 = skip + (size_t)N * 64;              // N*4
  float* ald1 = als1 + (size_t)N * 4;               // N*4
  float* als2 = ald1 + (size_t)N * 4;               // N
  float* ald2 = als2 + N;                           // N
  int* cnt = (int*)(ald2 + N);                      // N
  int* offs = cnt + N;                              // N+1
  int* cur = offs + N + 1;                          // N
  int* csrc = cur + N;                              // E
  int* bsum = csrc + E;                             // <=64
  int* boff = bsum + 64;                            // <=64

  const int gemm_rows = (N + 127) / 128;  // 391
  dim3 block256(256);
  const int wave_grid = (N * 64 + 255) / 256;  // 12500
  const int edge_grid = (E + 255) / 256;
  const int nb = (N + 1023) / 1024;

  hipLaunchKernelGGL(trcvt_kernel, dim3((65536 + 16384) / 256), block256, 0, stream,
                     W1, W2, W1t, W2t);
  hipLaunchKernelGGL((gemm_mfma<128, true, false, false, true, true>), dim3(gemm_rows, 2),
                     block256, 0, stream, x_noised, W1t, nullptr, xp1, N, 256,
                     a_src1, a_dst1, als1, ald1);
  hipLaunchKernelGGL((gemm_mfma<128, true, true, true, true, false>), dim3(gemm_rows, 2),
                     block256, 0, stream, x_clean, W1t, b1, hs, N, 256,
                     nullptr, nullptr, nullptr, nullptr);
  hipLaunchKernelGGL((gemm_mfma<64, false, true, false, false, false>), dim3(gemm_rows, 1),
                     block256, 0, stream, hs, W2t, b2, skip, N, 64,
                     nullptr, nullptr, nullptr, nullptr);
  hipMemsetAsync(cnt, 0, (size_t)N * sizeof(int), stream);
  hipLaunchKernelGGL(count_kernel, dim3(edge_grid), block256, 0, stream, edst, E, cnt);
  hipLaunchKernelGGL(scan_blocks, dim3(nb), block256, 0, stream, cnt, N, offs, bsum);
  hipLaunchKernelGGL(scan_top, dim3(1), dim3(64), 0, stream, bsum, nb, boff, offs, N);
  hipLaunchKernelGGL(scan_add, dim3(nb), block256, 0, stream, offs, cur, boff, N);
  hipLaunchKernelGGL(fill_kernel, dim3(edge_grid), block256, 0, stream, edst, esrc, E, cur, csrc);
  hipLaunchKernelGGL(agg1_kernel, dim3(wave_grid), block256, 0, stream,
                     xp1, als1, ald1, offs, csrc, b1, hs, N);
  hipLaunchKernelGGL((gemm_mfma<64, false, false, false, true, true>), dim3(gemm_rows, 1),
                     block256, 0, stream, hs, W2t, nullptr, xp2, N, 64,
                     a_src2, a_dst2, als2, ald2);
  hipLaunchKernelGGL(agg2_kernel, dim3(wave_grid), block256, 0, stream,
                     xp2, als2, ald2, offs, csrc, b2, skip, out, N);
}